// Round 1
// baseline (3149.231 us; speedup 1.0000x reference)
//
#include <hip/hip_runtime.h>
#include <hip/hip_bf16.h>
#include <math.h>

#define NN 50000
#define NE 600000
#define DD 128
#define HH 256
#define BN_EPS 1e-5f

// ---------------------------------------------------------------------------
// float atomic max via signed-max (v>=0) / unsigned-min (v<0) bit trick.
// Buffer initialized to -inf (0xFF800000). Invariant holds under any
// interleaving of the two ops (positive floats order as signed ints,
// negative floats order inversely as unsigned ints).
__device__ __forceinline__ void atomicMaxFloat(float* addr, float v) {
    if (v >= 0.0f) atomicMax((int*)addr, __float_as_int(v));
    else           atomicMin((unsigned int*)addr, __float_as_uint(v));
}

// ---------------------------------------------------------------------------
__global__ __launch_bounds__(256) void k_init(float4* __restrict__ agg_sum4,
                                              float4* __restrict__ agg_max4,
                                              float* __restrict__ stats) {
    int tid = blockIdx.x * 256 + threadIdx.x;
    const int n4 = NN * DD / 4;
    if (tid < n4) {
        agg_sum4[tid] = make_float4(0.f, 0.f, 0.f, 0.f);
        const float ni = -__builtin_inff();
        agg_max4[tid] = make_float4(ni, ni, ni, ni);
    }
    if (tid < 768) stats[tid] = 0.f;   // sum1[256] sumsq1[256] sum2[128] sumsq2[128]
}

// Transpose GRU weights (3D,D) -> (D,3D) so inner-loop lane access is coalesced.
__global__ __launch_bounds__(256) void k_transpose(const float* __restrict__ Wih,
                                                   const float* __restrict__ Whh,
                                                   float* __restrict__ WihT,
                                                   float* __restrict__ WhhT) {
    int tid = blockIdx.x * 256 + threadIdx.x;
    if (tid >= DD * 3 * DD) return;
    int k = tid / (3 * DD);
    int j = tid - k * (3 * DD);
    WihT[tid] = Wih[(size_t)j * DD + k];
    WhhT[tid] = Whh[(size_t)j * DD + k];
}

// ---------------------------------------------------------------------------
// Edge-parallel scatter: 32 threads per edge, float4 per thread.
__global__ __launch_bounds__(256) void k_scatter(const float4* __restrict__ x4,
                                                 const int* __restrict__ edges,
                                                 float* __restrict__ agg_sum,
                                                 float* __restrict__ agg_max) {
    int tid = blockIdx.x * 256 + threadIdx.x;
    int e = tid >> 5;
    if (e >= NE) return;
    int c = tid & 31;
    int src = edges[e];
    int dst = edges[NE + e];
    float4 v = x4[src * 32 + c];
    float* ps = agg_sum + (size_t)dst * DD + c * 4;
    float* pm = agg_max + (size_t)dst * DD + c * 4;
    atomicAdd(ps + 0, v.x);
    atomicAdd(ps + 1, v.y);
    atomicAdd(ps + 2, v.z);
    atomicAdd(ps + 3, v.w);
    atomicMaxFloat(pm + 0, v.x);
    atomicMaxFloat(pm + 1, v.y);
    atomicMaxFloat(pm + 2, v.z);
    atomicMaxFloat(pm + 3, v.w);
}

// ---------------------------------------------------------------------------
// Fused: agg = cat(sum,max(-inf->0)) @ merge_W + merge_b ; GRUCell(agg, x) -> h
// 16 rows per block, 256 threads: d = t&127 (output col), rh = t>>7 (row half).
__global__ __launch_bounds__(256) void k_merge_gru(
        const float* __restrict__ agg_sum, const float* __restrict__ agg_max,
        const float* __restrict__ x,
        const float* __restrict__ merge_W, const float* __restrict__ merge_b,
        const float* __restrict__ WihT, const float* __restrict__ WhhT,
        const float* __restrict__ b_ih, const float* __restrict__ b_hh,
        float* __restrict__ h_out) {
    __shared__ __align__(16) float cat_[16][2 * DD];
    __shared__ __align__(16) float xr_[16][DD];
    __shared__ __align__(16) float agg_[16][DD];
    int t = threadIdx.x;
    int r0 = blockIdx.x * 16;

    const float4* as4 = (const float4*)(agg_sum + (size_t)r0 * DD);
    const float4* am4 = (const float4*)(agg_max + (size_t)r0 * DD);
    const float4* x4  = (const float4*)(x + (size_t)r0 * DD);
    float4* cat4 = (float4*)cat_;
    float4* xr4  = (float4*)xr_;
    const float NINF = -__builtin_inff();
    #pragma unroll
    for (int ii = 0; ii < 4; ++ii) {
        int i = t + ii * 256;      // 1024 float4 = 16 rows x 256 floats
        int r = i >> 6;
        int cc = i & 63;
        float4 v;
        if (cc < 32) {
            v = as4[r * 32 + cc];
        } else {
            v = am4[r * 32 + (cc - 32)];
            v.x = (v.x == NINF) ? 0.f : v.x;
            v.y = (v.y == NINF) ? 0.f : v.y;
            v.z = (v.z == NINF) ? 0.f : v.z;
            v.w = (v.w == NINF) ? 0.f : v.w;
        }
        cat4[i] = v;
    }
    xr4[t]       = x4[t];
    xr4[t + 256] = x4[t + 256];
    __syncthreads();

    int d = t & 127;
    int rh = t >> 7;

    // merge linear: agg[r][d] = b[d] + sum_k cat[r][k] * merge_W[k][d]
    {
        float acc[8];
        float bd = merge_b[d];
        #pragma unroll
        for (int i = 0; i < 8; ++i) acc[i] = bd;
        for (int k = 0; k < 2 * DD; k += 4) {
            float w0 = merge_W[(k + 0) * DD + d];
            float w1 = merge_W[(k + 1) * DD + d];
            float w2 = merge_W[(k + 2) * DD + d];
            float w3 = merge_W[(k + 3) * DD + d];
            #pragma unroll
            for (int i = 0; i < 8; ++i) {
                float4 cv = *(const float4*)&cat_[rh * 8 + i][k];
                acc[i] = fmaf(cv.x, w0, fmaf(cv.y, w1, fmaf(cv.z, w2, fmaf(cv.w, w3, acc[i]))));
            }
        }
        #pragma unroll
        for (int i = 0; i < 8; ++i) agg_[rh * 8 + i][d] = acc[i];
    }
    __syncthreads();

    // GRU: gi = agg @ Wih^T + b_ih ; gh = x @ Whh^T + b_hh  (rows [r,z,n])
    float ir[8], iz[8], inn[8], hr[8], hz[8], hn[8];
    {
        float bi0 = b_ih[d], bi1 = b_ih[DD + d], bi2 = b_ih[2 * DD + d];
        float bh0 = b_hh[d], bh1 = b_hh[DD + d], bh2 = b_hh[2 * DD + d];
        #pragma unroll
        for (int i = 0; i < 8; ++i) {
            ir[i] = bi0; iz[i] = bi1; inn[i] = bi2;
            hr[i] = bh0; hz[i] = bh1; hn[i]  = bh2;
        }
    }
    for (int k = 0; k < DD; k += 4) {
        float wr[4], wz[4], wn[4], vr[4], vz[4], vn[4];
        #pragma unroll
        for (int q = 0; q < 4; ++q) {
            const float* Wi = WihT + (size_t)(k + q) * (3 * DD);
            const float* Wh = WhhT + (size_t)(k + q) * (3 * DD);
            wr[q] = Wi[d]; wz[q] = Wi[DD + d]; wn[q] = Wi[2 * DD + d];
            vr[q] = Wh[d]; vz[q] = Wh[DD + d]; vn[q] = Wh[2 * DD + d];
        }
        #pragma unroll
        for (int i = 0; i < 8; ++i) {
            float4 a4 = *(const float4*)&agg_[rh * 8 + i][k];
            float4 xv = *(const float4*)&xr_[rh * 8 + i][k];
            ir[i]  = fmaf(a4.x, wr[0], fmaf(a4.y, wr[1], fmaf(a4.z, wr[2], fmaf(a4.w, wr[3], ir[i]))));
            iz[i]  = fmaf(a4.x, wz[0], fmaf(a4.y, wz[1], fmaf(a4.z, wz[2], fmaf(a4.w, wz[3], iz[i]))));
            inn[i] = fmaf(a4.x, wn[0], fmaf(a4.y, wn[1], fmaf(a4.z, wn[2], fmaf(a4.w, wn[3], inn[i]))));
            hr[i]  = fmaf(xv.x, vr[0], fmaf(xv.y, vr[1], fmaf(xv.z, vr[2], fmaf(xv.w, vr[3], hr[i]))));
            hz[i]  = fmaf(xv.x, vz[0], fmaf(xv.y, vz[1], fmaf(xv.z, vz[2], fmaf(xv.w, vz[3], hz[i]))));
            hn[i]  = fmaf(xv.x, vn[0], fmaf(xv.y, vn[1], fmaf(xv.z, vn[2], fmaf(xv.w, vn[3], hn[i]))));
        }
    }
    #pragma unroll
    for (int i = 0; i < 8; ++i) {
        int row = r0 + rh * 8 + i;
        float r = 1.f / (1.f + __expf(-(ir[i] + hr[i])));
        float z = 1.f / (1.f + __expf(-(iz[i] + hz[i])));
        float n = tanhf(inn[i] + r * hn[i]);
        float xv = xr_[rh * 8 + i][d];
        h_out[(size_t)row * DD + d] = (1.f - z) * n + z * xv;
    }
}

// ---------------------------------------------------------------------------
// s1 = leaky(h @ W1 + b1), plus per-column sum / sumsq partials.
__global__ __launch_bounds__(256) void k_mlp1(const float* __restrict__ h,
        const float* __restrict__ W1, const float* __restrict__ b1,
        float* __restrict__ s1, float* __restrict__ sum1, float* __restrict__ sumsq1) {
    __shared__ __align__(16) float hs[16][DD];
    int t = threadIdx.x;
    int r0 = blockIdx.x * 16;
    const float4* h4 = (const float4*)(h + (size_t)r0 * DD);
    float4* hs4 = (float4*)hs;
    hs4[t]       = h4[t];
    hs4[t + 256] = h4[t + 256];
    __syncthreads();
    int j = t;                      // output column 0..255
    float acc[16];
    float bj = b1[j];
    #pragma unroll
    for (int i = 0; i < 16; ++i) acc[i] = bj;
    for (int k = 0; k < DD; k += 4) {
        float w0 = W1[(k + 0) * HH + j];
        float w1 = W1[(k + 1) * HH + j];
        float w2 = W1[(k + 2) * HH + j];
        float w3 = W1[(k + 3) * HH + j];
        #pragma unroll
        for (int i = 0; i < 16; ++i) {
            float4 hv = *(const float4*)&hs[i][k];
            acc[i] = fmaf(hv.x, w0, fmaf(hv.y, w1, fmaf(hv.z, w2, fmaf(hv.w, w3, acc[i]))));
        }
    }
    float s = 0.f, sq = 0.f;
    #pragma unroll
    for (int i = 0; i < 16; ++i) {
        float v = acc[i];
        v = (v >= 0.f) ? v : 0.01f * v;
        s1[(size_t)(r0 + i) * HH + j] = v;
        s += v; sq += v * v;
    }
    atomicAdd(&sum1[j], s);
    atomicAdd(&sumsq1[j], sq);
}

// Fold BN1 affine into W2: W2p = a1[:,None]*W2, b2p = b2 + c1 @ W2.
__global__ __launch_bounds__(256) void k_prep2(const float* __restrict__ sum1,
        const float* __restrict__ sumsq1,
        const float* __restrict__ gamma1, const float* __restrict__ beta1,
        const float* __restrict__ W2, const float* __restrict__ b2,
        float* __restrict__ W2p, float* __restrict__ b2p) {
    __shared__ float a1s[HH], c1s[HH];
    int t = threadIdx.x;
    {
        float m = sum1[t] * (1.f / NN);
        float var = sumsq1[t] * (1.f / NN) - m * m;
        float a = gamma1[t] * rsqrtf(var + BN_EPS);
        a1s[t] = a;
        c1s[t] = beta1[t] - a * m;
    }
    __syncthreads();
    for (int idx = t; idx < HH * DD; idx += 256) {
        int k = idx >> 7;
        W2p[idx] = a1s[k] * W2[idx];
    }
    if (t < DD) {
        float acc = b2[t];
        for (int k = 0; k < HH; ++k) acc = fmaf(c1s[k], W2[k * DD + t], acc);
        b2p[t] = acc;
    }
}

// s2 = leaky(s1 @ W2p + b2p), plus per-column stats.
__global__ __launch_bounds__(256) void k_mlp2(const float* __restrict__ s1,
        const float* __restrict__ W2p, const float* __restrict__ b2p,
        float* __restrict__ s2, float* __restrict__ sum2, float* __restrict__ sumsq2) {
    __shared__ __align__(16) float ss[16][HH];
    int t = threadIdx.x;
    int r0 = blockIdx.x * 16;
    const float4* s14 = (const float4*)(s1 + (size_t)r0 * HH);
    float4* ss4 = (float4*)ss;
    #pragma unroll
    for (int i = 0; i < 4; ++i) ss4[t + i * 256] = s14[t + i * 256];
    __syncthreads();
    int d = t & 127;
    int rh = t >> 7;
    float acc[8];
    float bd = b2p[d];
    #pragma unroll
    for (int i = 0; i < 8; ++i) acc[i] = bd;
    for (int k = 0; k < HH; k += 4) {
        float w0 = W2p[(k + 0) * DD + d];
        float w1 = W2p[(k + 1) * DD + d];
        float w2 = W2p[(k + 2) * DD + d];
        float w3 = W2p[(k + 3) * DD + d];
        #pragma unroll
        for (int i = 0; i < 8; ++i) {
            float4 sv = *(const float4*)&ss[rh * 8 + i][k];
            acc[i] = fmaf(sv.x, w0, fmaf(sv.y, w1, fmaf(sv.z, w2, fmaf(sv.w, w3, acc[i]))));
        }
    }
    float s = 0.f, sq = 0.f;
    #pragma unroll
    for (int i = 0; i < 8; ++i) {
        float v = acc[i];
        v = (v >= 0.f) ? v : 0.01f * v;
        s2[(size_t)(r0 + rh * 8 + i) * DD + d] = v;
        s += v; sq += v * v;
    }
    atomicAdd(&sum2[d], s);
    atomicAdd(&sumsq2[d], sq);
}

// out = a2 * s2 + c2 (BN2 applied elementwise).
__global__ __launch_bounds__(256) void k_bn_out(const float* __restrict__ s2,
        const float* __restrict__ sum2, const float* __restrict__ sumsq2,
        const float* __restrict__ gamma2, const float* __restrict__ beta2,
        float* __restrict__ out) {
    __shared__ float a2s[DD], c2s[DD];
    int t = threadIdx.x;
    if (t < DD) {
        float m = sum2[t] * (1.f / NN);
        float var = sumsq2[t] * (1.f / NN) - m * m;
        float a = gamma2[t] * rsqrtf(var + BN_EPS);
        a2s[t] = a;
        c2s[t] = beta2[t] - a * m;
    }
    __syncthreads();
    int tid = blockIdx.x * 256 + t;
    if (tid >= NN * DD / 4) return;
    int c4 = (tid & 31) * 4;
    float4 v = ((const float4*)s2)[tid];
    float4 o;
    o.x = a2s[c4 + 0] * v.x + c2s[c4 + 0];
    o.y = a2s[c4 + 1] * v.y + c2s[c4 + 1];
    o.z = a2s[c4 + 2] * v.z + c2s[c4 + 2];
    o.w = a2s[c4 + 3] * v.w + c2s[c4 + 3];
    ((float4*)out)[tid] = o;
}

// ---------------------------------------------------------------------------
extern "C" void kernel_launch(void* const* d_in, const int* in_sizes, int n_in,
                              void* d_out, int out_size, void* d_ws, size_t ws_size,
                              hipStream_t stream) {
    const float* x       = (const float*)d_in[0];
    const int*   edges   = (const int*)d_in[1];
    const float* merge_W = (const float*)d_in[2];
    const float* merge_b = (const float*)d_in[3];
    const float* W_ih    = (const float*)d_in[4];
    const float* W_hh    = (const float*)d_in[5];
    const float* b_ih    = (const float*)d_in[6];
    const float* b_hh    = (const float*)d_in[7];
    const float* W1      = (const float*)d_in[8];
    const float* b1      = (const float*)d_in[9];
    const float* gamma1  = (const float*)d_in[10];
    const float* beta1   = (const float*)d_in[11];
    const float* W2      = (const float*)d_in[12];
    const float* b2      = (const float*)d_in[13];
    const float* gamma2  = (const float*)d_in[14];
    const float* beta2   = (const float*)d_in[15];
    float* out = (float*)d_out;

    // ws layout (floats). Region A (12.8M): agg_sum+agg_max, later s1.
    // Region B (6.4M): h, later s2. Then stats + transposed/folded weights.
    float* ws      = (float*)d_ws;
    float* agg_sum = ws;                         // 6,400,000
    float* agg_max = ws + 6400000;               // 6,400,000
    float* s1      = ws;                         // 12,800,000 (reuses A after scatter+gru)
    float* h       = ws + 12800000;              // 6,400,000
    float* s2      = h;                          // reuses B after mlp1
    float* stats   = ws + 19200000;              // 768
    float* sum1    = stats;
    float* sumsq1  = stats + 256;
    float* sum2    = stats + 512;
    float* sumsq2  = stats + 640;
    float* WihT    = ws + 19200768;              // 49,152
    float* WhhT    = WihT + 49152;               // 49,152
    float* W2p     = WhhT + 49152;               // 32,768
    float* b2p     = W2p + 32768;                // 128
    // total ~19.33M floats = 77.3 MB of ws

    k_init<<<6250, 256, 0, stream>>>((float4*)agg_sum, (float4*)agg_max, stats);
    k_transpose<<<192, 256, 0, stream>>>(W_ih, W_hh, WihT, WhhT);
    k_scatter<<<(NE * 32) / 256, 256, 0, stream>>>((const float4*)x, edges, agg_sum, agg_max);
    k_merge_gru<<<NN / 16, 256, 0, stream>>>(agg_sum, agg_max, x, merge_W, merge_b,
                                             WihT, WhhT, b_ih, b_hh, h);
    k_mlp1<<<NN / 16, 256, 0, stream>>>(h, W1, b1, s1, sum1, sumsq1);
    k_prep2<<<1, 256, 0, stream>>>(sum1, sumsq1, gamma1, beta1, W2, b2, W2p, b2p);
    k_mlp2<<<NN / 16, 256, 0, stream>>>(s1, W2p, b2p, s2, sum2, sumsq2);
    k_bn_out<<<6250, 256, 0, stream>>>(s2, sum2, sumsq2, gamma2, beta2, out);
}

// Round 2
// 860.710 us; speedup vs baseline: 3.6589x; 3.6589x over previous
//
#include <hip/hip_runtime.h>
#include <hip/hip_bf16.h>
#include <math.h>

#define NN 50000
#define NE 600000
#define DD 128
#define HH 256
#define BN_EPS 1e-5f

// ---------------------------------------------------------------------------
// init: zero degree counters + BN stats accumulators.
__global__ __launch_bounds__(256) void k_init(int* __restrict__ deg,
                                              float* __restrict__ stats) {
    int tid = blockIdx.x * 256 + threadIdx.x;
    if (tid < NN) deg[tid] = 0;
    if (tid < 768) stats[tid] = 0.f;   // sum1[256] sumsq1[256] sum2[128] sumsq2[128]
}

// Count in-degree of each dst node.
__global__ __launch_bounds__(256) void k_count(const int* __restrict__ edges,
                                               int* __restrict__ deg) {
    int e = blockIdx.x * 256 + threadIdx.x;
    if (e >= NE) return;
    atomicAdd(&deg[edges[NE + e]], 1);
}

// Single-block exclusive scan of deg[NN] -> rowptr[NN+1], cursor[NN].
__global__ __launch_bounds__(1024) void k_scan(const int* __restrict__ deg,
                                               int* __restrict__ rowptr,
                                               int* __restrict__ cursor) {
    __shared__ int part[1024];
    int t = threadIdx.x;
    const int CH = (NN + 1023) / 1024;   // 49
    int base = t * CH;
    int s = 0;
    for (int i = 0; i < CH; ++i) {
        int idx = base + i;
        if (idx < NN) s += deg[idx];
    }
    part[t] = s;
    __syncthreads();
    for (int off = 1; off < 1024; off <<= 1) {
        int v = 0;
        if (t >= off) v = part[t - off];
        __syncthreads();
        if (t >= off) part[t] += v;
        __syncthreads();
    }
    int run = (t > 0) ? part[t - 1] : 0;
    for (int i = 0; i < CH; ++i) {
        int idx = base + i;
        if (idx < NN) {
            rowptr[idx] = run;
            cursor[idx] = run;
            run += deg[idx];
        }
    }
    if (t == 1023) rowptr[NN] = part[1023];
}

// Place each edge's src into its dst's CSR slot.
__global__ __launch_bounds__(256) void k_fill(const int* __restrict__ edges,
                                              int* __restrict__ cursor,
                                              int* __restrict__ eidx) {
    int e = blockIdx.x * 256 + threadIdx.x;
    if (e >= NE) return;
    int src = edges[e];
    int dst = edges[NE + e];
    int slot = atomicAdd(&cursor[dst], 1);
    eidx[slot] = src;
}

// One wave (64 lanes) per node: gather x[src] rows, reduce sum+max in regs.
__global__ __launch_bounds__(256) void k_aggregate(const float2* __restrict__ x2,
        const int* __restrict__ rowptr, const int* __restrict__ eidx,
        float2* __restrict__ sum2, float2* __restrict__ max2) {
    int gid = blockIdx.x * 256 + threadIdx.x;
    int node = gid >> 6;
    int lane = threadIdx.x & 63;
    if (node >= NN) return;
    int beg = rowptr[node], end = rowptr[node + 1];
    float2 s = make_float2(0.f, 0.f);
    const float NINF = -__builtin_inff();
    float2 m = make_float2(NINF, NINF);
    for (int j = beg; j < end; ++j) {
        int src = eidx[j];
        float2 v = x2[(size_t)src * 64 + lane];
        s.x += v.x; s.y += v.y;
        m.x = fmaxf(m.x, v.x);
        m.y = fmaxf(m.y, v.y);
    }
    if (beg == end) m = make_float2(0.f, 0.f);
    sum2[(size_t)node * 64 + lane] = s;
    max2[(size_t)node * 64 + lane] = m;
}

// Transpose GRU weights (3D,D) -> (D,3D) so inner-loop lane access is coalesced.
__global__ __launch_bounds__(256) void k_transpose(const float* __restrict__ Wih,
                                                   const float* __restrict__ Whh,
                                                   float* __restrict__ WihT,
                                                   float* __restrict__ WhhT) {
    int tid = blockIdx.x * 256 + threadIdx.x;
    if (tid >= DD * 3 * DD) return;
    int k = tid / (3 * DD);
    int j = tid - k * (3 * DD);
    WihT[tid] = Wih[(size_t)j * DD + k];
    WhhT[tid] = Whh[(size_t)j * DD + k];
}

// ---------------------------------------------------------------------------
// Fused: agg = cat(sum,max) @ merge_W + merge_b ; GRUCell(agg, x) -> h
// 16 rows per block, 256 threads: d = t&127 (output col), rh = t>>7 (row half).
__global__ __launch_bounds__(256) void k_merge_gru(
        const float* __restrict__ agg_sum, const float* __restrict__ agg_max,
        const float* __restrict__ x,
        const float* __restrict__ merge_W, const float* __restrict__ merge_b,
        const float* __restrict__ WihT, const float* __restrict__ WhhT,
        const float* __restrict__ b_ih, const float* __restrict__ b_hh,
        float* __restrict__ h_out) {
    __shared__ __align__(16) float cat_[16][2 * DD];
    __shared__ __align__(16) float xr_[16][DD];
    __shared__ __align__(16) float agg_[16][DD];
    int t = threadIdx.x;
    int r0 = blockIdx.x * 16;

    const float4* as4 = (const float4*)(agg_sum + (size_t)r0 * DD);
    const float4* am4 = (const float4*)(agg_max + (size_t)r0 * DD);
    const float4* x4  = (const float4*)(x + (size_t)r0 * DD);
    float4* cat4 = (float4*)cat_;
    float4* xr4  = (float4*)xr_;
    #pragma unroll
    for (int ii = 0; ii < 4; ++ii) {
        int i = t + ii * 256;      // 1024 float4 = 16 rows x 256 floats
        int r = i >> 6;
        int cc = i & 63;
        float4 v;
        if (cc < 32) v = as4[r * 32 + cc];
        else         v = am4[r * 32 + (cc - 32)];
        cat4[i] = v;
    }
    xr4[t]       = x4[t];
    xr4[t + 256] = x4[t + 256];
    __syncthreads();

    int d = t & 127;
    int rh = t >> 7;

    // merge linear: agg[r][d] = b[d] + sum_k cat[r][k] * merge_W[k][d]
    {
        float acc[8];
        float bd = merge_b[d];
        #pragma unroll
        for (int i = 0; i < 8; ++i) acc[i] = bd;
        for (int k = 0; k < 2 * DD; k += 4) {
            float w0 = merge_W[(k + 0) * DD + d];
            float w1 = merge_W[(k + 1) * DD + d];
            float w2 = merge_W[(k + 2) * DD + d];
            float w3 = merge_W[(k + 3) * DD + d];
            #pragma unroll
            for (int i = 0; i < 8; ++i) {
                float4 cv = *(const float4*)&cat_[rh * 8 + i][k];
                acc[i] = fmaf(cv.x, w0, fmaf(cv.y, w1, fmaf(cv.z, w2, fmaf(cv.w, w3, acc[i]))));
            }
        }
        #pragma unroll
        for (int i = 0; i < 8; ++i) agg_[rh * 8 + i][d] = acc[i];
    }
    __syncthreads();

    // GRU: gi = agg @ Wih^T + b_ih ; gh = x @ Whh^T + b_hh  (rows [r,z,n])
    float ir[8], iz[8], inn[8], hr[8], hz[8], hn[8];
    {
        float bi0 = b_ih[d], bi1 = b_ih[DD + d], bi2 = b_ih[2 * DD + d];
        float bh0 = b_hh[d], bh1 = b_hh[DD + d], bh2 = b_hh[2 * DD + d];
        #pragma unroll
        for (int i = 0; i < 8; ++i) {
            ir[i] = bi0; iz[i] = bi1; inn[i] = bi2;
            hr[i] = bh0; hz[i] = bh1; hn[i]  = bh2;
        }
    }
    for (int k = 0; k < DD; k += 4) {
        float wr[4], wz[4], wn[4], vr[4], vz[4], vn[4];
        #pragma unroll
        for (int q = 0; q < 4; ++q) {
            const float* Wi = WihT + (size_t)(k + q) * (3 * DD);
            const float* Wh = WhhT + (size_t)(k + q) * (3 * DD);
            wr[q] = Wi[d]; wz[q] = Wi[DD + d]; wn[q] = Wi[2 * DD + d];
            vr[q] = Wh[d]; vz[q] = Wh[DD + d]; vn[q] = Wh[2 * DD + d];
        }
        #pragma unroll
        for (int i = 0; i < 8; ++i) {
            float4 a4 = *(const float4*)&agg_[rh * 8 + i][k];
            float4 xv = *(const float4*)&xr_[rh * 8 + i][k];
            ir[i]  = fmaf(a4.x, wr[0], fmaf(a4.y, wr[1], fmaf(a4.z, wr[2], fmaf(a4.w, wr[3], ir[i]))));
            iz[i]  = fmaf(a4.x, wz[0], fmaf(a4.y, wz[1], fmaf(a4.z, wz[2], fmaf(a4.w, wz[3], iz[i]))));
            inn[i] = fmaf(a4.x, wn[0], fmaf(a4.y, wn[1], fmaf(a4.z, wn[2], fmaf(a4.w, wn[3], inn[i]))));
            hr[i]  = fmaf(xv.x, vr[0], fmaf(xv.y, vr[1], fmaf(xv.z, vr[2], fmaf(xv.w, vr[3], hr[i]))));
            hz[i]  = fmaf(xv.x, vz[0], fmaf(xv.y, vz[1], fmaf(xv.z, vz[2], fmaf(xv.w, vz[3], hz[i]))));
            hn[i]  = fmaf(xv.x, vn[0], fmaf(xv.y, vn[1], fmaf(xv.z, vn[2], fmaf(xv.w, vn[3], hn[i]))));
        }
    }
    #pragma unroll
    for (int i = 0; i < 8; ++i) {
        int row = r0 + rh * 8 + i;
        float r = 1.f / (1.f + __expf(-(ir[i] + hr[i])));
        float z = 1.f / (1.f + __expf(-(iz[i] + hz[i])));
        float n = tanhf(inn[i] + r * hn[i]);
        float xv = xr_[rh * 8 + i][d];
        h_out[(size_t)row * DD + d] = (1.f - z) * n + z * xv;
    }
}

// ---------------------------------------------------------------------------
// s1 = leaky(h @ W1 + b1), plus per-column sum / sumsq partials.
__global__ __launch_bounds__(256) void k_mlp1(const float* __restrict__ h,
        const float* __restrict__ W1, const float* __restrict__ b1,
        float* __restrict__ s1, float* __restrict__ sum1, float* __restrict__ sumsq1) {
    __shared__ __align__(16) float hs[16][DD];
    int t = threadIdx.x;
    int r0 = blockIdx.x * 16;
    const float4* h4 = (const float4*)(h + (size_t)r0 * DD);
    float4* hs4 = (float4*)hs;
    hs4[t]       = h4[t];
    hs4[t + 256] = h4[t + 256];
    __syncthreads();
    int j = t;                      // output column 0..255
    float acc[16];
    float bj = b1[j];
    #pragma unroll
    for (int i = 0; i < 16; ++i) acc[i] = bj;
    for (int k = 0; k < DD; k += 4) {
        float w0 = W1[(k + 0) * HH + j];
        float w1 = W1[(k + 1) * HH + j];
        float w2 = W1[(k + 2) * HH + j];
        float w3 = W1[(k + 3) * HH + j];
        #pragma unroll
        for (int i = 0; i < 16; ++i) {
            float4 hv = *(const float4*)&hs[i][k];
            acc[i] = fmaf(hv.x, w0, fmaf(hv.y, w1, fmaf(hv.z, w2, fmaf(hv.w, w3, acc[i]))));
        }
    }
    float s = 0.f, sq = 0.f;
    #pragma unroll
    for (int i = 0; i < 16; ++i) {
        float v = acc[i];
        v = (v >= 0.f) ? v : 0.01f * v;
        s1[(size_t)(r0 + i) * HH + j] = v;
        s += v; sq += v * v;
    }
    atomicAdd(&sum1[j], s);
    atomicAdd(&sumsq1[j], sq);
}

// Fold BN1 affine into W2: W2p = a1[:,None]*W2, b2p = b2 + c1 @ W2.
__global__ __launch_bounds__(256) void k_prep2(const float* __restrict__ sum1,
        const float* __restrict__ sumsq1,
        const float* __restrict__ gamma1, const float* __restrict__ beta1,
        const float* __restrict__ W2, const float* __restrict__ b2,
        float* __restrict__ W2p, float* __restrict__ b2p) {
    __shared__ float a1s[HH], c1s[HH];
    int t = threadIdx.x;
    {
        float m = sum1[t] * (1.f / NN);
        float var = sumsq1[t] * (1.f / NN) - m * m;
        float a = gamma1[t] * rsqrtf(var + BN_EPS);
        a1s[t] = a;
        c1s[t] = beta1[t] - a * m;
    }
    __syncthreads();
    for (int idx = t; idx < HH * DD; idx += 256) {
        int k = idx >> 7;
        W2p[idx] = a1s[k] * W2[idx];
    }
    if (t < DD) {
        float acc = b2[t];
        for (int k = 0; k < HH; ++k) acc = fmaf(c1s[k], W2[k * DD + t], acc);
        b2p[t] = acc;
    }
}

// s2 = leaky(s1 @ W2p + b2p), plus per-column stats.
__global__ __launch_bounds__(256) void k_mlp2(const float* __restrict__ s1,
        const float* __restrict__ W2p, const float* __restrict__ b2p,
        float* __restrict__ s2, float* __restrict__ sum2, float* __restrict__ sumsq2) {
    __shared__ __align__(16) float ss[16][HH];
    int t = threadIdx.x;
    int r0 = blockIdx.x * 16;
    const float4* s14 = (const float4*)(s1 + (size_t)r0 * HH);
    float4* ss4 = (float4*)ss;
    #pragma unroll
    for (int i = 0; i < 4; ++i) ss4[t + i * 256] = s14[t + i * 256];
    __syncthreads();
    int d = t & 127;
    int rh = t >> 7;
    float acc[8];
    float bd = b2p[d];
    #pragma unroll
    for (int i = 0; i < 8; ++i) acc[i] = bd;
    for (int k = 0; k < HH; k += 4) {
        float w0 = W2p[(k + 0) * DD + d];
        float w1 = W2p[(k + 1) * DD + d];
        float w2 = W2p[(k + 2) * DD + d];
        float w3 = W2p[(k + 3) * DD + d];
        #pragma unroll
        for (int i = 0; i < 8; ++i) {
            float4 sv = *(const float4*)&ss[rh * 8 + i][k];
            acc[i] = fmaf(sv.x, w0, fmaf(sv.y, w1, fmaf(sv.z, w2, fmaf(sv.w, w3, acc[i]))));
        }
    }
    float s = 0.f, sq = 0.f;
    #pragma unroll
    for (int i = 0; i < 8; ++i) {
        float v = acc[i];
        v = (v >= 0.f) ? v : 0.01f * v;
        s2[(size_t)(r0 + rh * 8 + i) * DD + d] = v;
        s += v; sq += v * v;
    }
    atomicAdd(&sum2[d], s);
    atomicAdd(&sumsq2[d], sq);
}

// out = a2 * s2 + c2 (BN2 applied elementwise).
__global__ __launch_bounds__(256) void k_bn_out(const float* __restrict__ s2,
        const float* __restrict__ sum2, const float* __restrict__ sumsq2,
        const float* __restrict__ gamma2, const float* __restrict__ beta2,
        float* __restrict__ out) {
    __shared__ float a2s[DD], c2s[DD];
    int t = threadIdx.x;
    if (t < DD) {
        float m = sum2[t] * (1.f / NN);
        float var = sumsq2[t] * (1.f / NN) - m * m;
        float a = gamma2[t] * rsqrtf(var + BN_EPS);
        a2s[t] = a;
        c2s[t] = beta2[t] - a * m;
    }
    __syncthreads();
    int tid = blockIdx.x * 256 + t;
    if (tid >= NN * DD / 4) return;
    int c4 = (tid & 31) * 4;
    float4 v = ((const float4*)s2)[tid];
    float4 o;
    o.x = a2s[c4 + 0] * v.x + c2s[c4 + 0];
    o.y = a2s[c4 + 1] * v.y + c2s[c4 + 1];
    o.z = a2s[c4 + 2] * v.z + c2s[c4 + 2];
    o.w = a2s[c4 + 3] * v.w + c2s[c4 + 3];
    ((float4*)out)[tid] = o;
}

// ---------------------------------------------------------------------------
extern "C" void kernel_launch(void* const* d_in, const int* in_sizes, int n_in,
                              void* d_out, int out_size, void* d_ws, size_t ws_size,
                              hipStream_t stream) {
    const float* x       = (const float*)d_in[0];
    const int*   edges   = (const int*)d_in[1];
    const float* merge_W = (const float*)d_in[2];
    const float* merge_b = (const float*)d_in[3];
    const float* W_ih    = (const float*)d_in[4];
    const float* W_hh    = (const float*)d_in[5];
    const float* b_ih    = (const float*)d_in[6];
    const float* b_hh    = (const float*)d_in[7];
    const float* W1      = (const float*)d_in[8];
    const float* b1      = (const float*)d_in[9];
    const float* gamma1  = (const float*)d_in[10];
    const float* beta1   = (const float*)d_in[11];
    const float* W2      = (const float*)d_in[12];
    const float* b2      = (const float*)d_in[13];
    const float* gamma2  = (const float*)d_in[14];
    const float* beta2   = (const float*)d_in[15];
    float* out = (float*)d_out;

    // ws layout (floats):
    // Region A [0, 12.8M): agg_sum + agg_max, later reused as s1.
    // Region B [12.8M, 19.2M): eidx (ints, during CSR+aggregate), then h / s2.
    // [19.2M, ...): stats, transposed/folded weights, CSR rowptr/cursor/deg.
    float* ws      = (float*)d_ws;
    float* agg_sum = ws;                         // 6,400,000
    float* agg_max = ws + 6400000;               // 6,400,000
    float* s1      = ws;                         // reuses A after merge_gru
    float* h       = ws + 12800000;              // 6,400,000 (after eidx is dead)
    float* s2      = h;                          // reuses B after mlp1
    int*   eidx    = (int*)(ws + 12800000);      // 600,000 ints (dead once aggregated)
    float* stats   = ws + 19200000;              // 768
    float* sum1    = stats;
    float* sumsq1  = stats + 256;
    float* sum2    = stats + 512;
    float* sumsq2  = stats + 640;
    float* WihT    = ws + 19200768;              // 49,152
    float* WhhT    = WihT + 49152;               // 49,152
    float* W2p     = WhhT + 49152;               // 32,768
    float* b2p     = W2p + 32768;                // 128
    int*   deg     = (int*)(b2p + 128);          // 50,000
    int*   rowptr  = deg + NN;                   // 50,001
    int*   cursor  = rowptr + NN + 1;            // 50,000
    // total ~19.48M floats = 78 MB of ws

    k_init<<<(NN + 255) / 256, 256, 0, stream>>>(deg, stats);
    k_count<<<(NE + 255) / 256, 256, 0, stream>>>(edges, deg);
    k_scan<<<1, 1024, 0, stream>>>(deg, rowptr, cursor);
    k_fill<<<(NE + 255) / 256, 256, 0, stream>>>(edges, cursor, eidx);
    k_transpose<<<192, 256, 0, stream>>>(W_ih, W_hh, WihT, WhhT);
    k_aggregate<<<(NN * 64) / 256, 256, 0, stream>>>((const float2*)x, rowptr, eidx,
                                                     (float2*)agg_sum, (float2*)agg_max);
    k_merge_gru<<<NN / 16, 256, 0, stream>>>(agg_sum, agg_max, x, merge_W, merge_b,
                                             WihT, WhhT, b_ih, b_hh, h);
    k_mlp1<<<NN / 16, 256, 0, stream>>>(h, W1, b1, s1, sum1, sumsq1);
    k_prep2<<<1, 256, 0, stream>>>(sum1, sumsq1, gamma1, beta1, W2, b2, W2p, b2p);
    k_mlp2<<<NN / 16, 256, 0, stream>>>(s1, W2p, b2p, s2, sum2, sumsq2);
    k_bn_out<<<6250, 256, 0, stream>>>(s2, sum2, sumsq2, gamma2, beta2, out);
}

// Round 4
// 578.698 us; speedup vs baseline: 5.4419x; 1.4873x over previous
//
#include <hip/hip_runtime.h>
#include <hip/hip_bf16.h>
#include <math.h>

#define NN 50000
#define NE 600000
#define DD 128
#define HH 256
#define BN_EPS 1e-5f

typedef unsigned short u16;
typedef short bf16x8 __attribute__((ext_vector_type(8)));
typedef float f32x4 __attribute__((ext_vector_type(4)));

__device__ __forceinline__ u16 f2bf(float f) {
    unsigned int u = __float_as_uint(f);
    unsigned int r = (u + 0x7fffu + ((u >> 16) & 1u)) >> 16;
    return (u16)r;
}
__device__ __forceinline__ float bf2f(u16 b) {
    return __uint_as_float(((unsigned int)b) << 16);
}
#define MFMA(a, b, c) __builtin_amdgcn_mfma_f32_16x16x32_bf16((a), (b), (c), 0, 0, 0)

// ---------------------------------------------------------------------------
__global__ __launch_bounds__(256) void k_init(int* __restrict__ deg,
                                              float* __restrict__ stats) {
    int tid = blockIdx.x * 256 + threadIdx.x;
    if (tid < NN) deg[tid] = 0;
    if (tid < 768) stats[tid] = 0.f;
}

__global__ __launch_bounds__(256) void k_count(const int* __restrict__ edges,
                                               int* __restrict__ deg) {
    int e = blockIdx.x * 256 + threadIdx.x;
    if (e >= NE) return;
    atomicAdd(&deg[edges[NE + e]], 1);
}

__global__ __launch_bounds__(1024) void k_scan(const int* __restrict__ deg,
                                               int* __restrict__ rowptr,
                                               int* __restrict__ cursor) {
    __shared__ int part[1024];
    int t = threadIdx.x;
    const int CH = (NN + 1023) / 1024;
    int base = t * CH;
    int s = 0;
    for (int i = 0; i < CH; ++i) {
        int idx = base + i;
        if (idx < NN) s += deg[idx];
    }
    part[t] = s;
    __syncthreads();
    for (int off = 1; off < 1024; off <<= 1) {
        int v = 0;
        if (t >= off) v = part[t - off];
        __syncthreads();
        if (t >= off) part[t] += v;
        __syncthreads();
    }
    int run = (t > 0) ? part[t - 1] : 0;
    for (int i = 0; i < CH; ++i) {
        int idx = base + i;
        if (idx < NN) {
            rowptr[idx] = run;
            cursor[idx] = run;
            run += deg[idx];
        }
    }
    if (t == 1023) rowptr[NN] = part[1023];
}

__global__ __launch_bounds__(256) void k_fill(const int* __restrict__ edges,
                                              int* __restrict__ cursor,
                                              int* __restrict__ eidx) {
    int e = blockIdx.x * 256 + threadIdx.x;
    if (e >= NE) return;
    int src = edges[e];
    int dst = edges[NE + e];
    int slot = atomicAdd(&cursor[dst], 1);
    eidx[slot] = src;
}

// x f32 -> bf16 (8 elems/thread)
__global__ __launch_bounds__(256) void k_xcast(const float4* __restrict__ x4,
                                               uint4* __restrict__ xb4) {
    int tid = blockIdx.x * 256 + threadIdx.x;
    if (tid >= NN * DD / 8) return;
    float4 a = x4[tid * 2];
    float4 b = x4[tid * 2 + 1];
    uint4 o;
    o.x = (unsigned)f2bf(a.x) | ((unsigned)f2bf(a.y) << 16);
    o.y = (unsigned)f2bf(a.z) | ((unsigned)f2bf(a.w) << 16);
    o.z = (unsigned)f2bf(b.x) | ((unsigned)f2bf(b.y) << 16);
    o.w = (unsigned)f2bf(b.z) | ((unsigned)f2bf(b.w) << 16);
    xb4[tid] = o;
}

// ---------------------------------------------------------------------------
// One wave per node, 2 cols/lane (4B loads from bf16 x), f32 accumulate,
// bf16 store of agg_sum / agg_max.
__global__ __launch_bounds__(256) void k_aggregate(const unsigned* __restrict__ xb,
        const int* __restrict__ rowptr, const int* __restrict__ eidx,
        unsigned* __restrict__ asum, unsigned* __restrict__ amax) {
    int gid = blockIdx.x * 256 + threadIdx.x;
    int node = gid >> 6;
    int lane = threadIdx.x & 63;
    if (node >= NN) return;
    int beg = rowptr[node], end = rowptr[node + 1];
    float sx = 0.f, sy = 0.f;
    const float NINF = -__builtin_inff();
    float mx = NINF, my = NINF;
    for (int j = beg; j < end; ++j) {
        int src = eidx[j];
        unsigned v = xb[(size_t)src * 64 + lane];
        float vx = bf2f((u16)(v & 0xffff));
        float vy = bf2f((u16)(v >> 16));
        sx += vx; sy += vy;
        mx = fmaxf(mx, vx); my = fmaxf(my, vy);
    }
    if (beg == end) { mx = 0.f; my = 0.f; }
    asum[(size_t)node * 64 + lane] = (unsigned)f2bf(sx) | ((unsigned)f2bf(sy) << 16);
    amax[(size_t)node * 64 + lane] = (unsigned)f2bf(mx) | ((unsigned)f2bf(my) << 16);
}

// ---------------------------------------------------------------------------
// Pack helper: B-fragment layout for mfma_f32_16x16x32_bf16.
// lane l holds B[k=(l>>4)*8+e][n=l&15]; flat = ((nt*KT+kt)*64+l)*8+e.
__device__ __forceinline__ size_t packB(int k, int n, int KT) {
    int nt = n >> 4;
    int kt = k >> 5;
    int lane = (n & 15) | (((k >> 3) & 3) << 4);
    int e = k & 7;
    return ((size_t)(nt * KT + kt) * 64 + lane) * 8 + e;
}

// W_gru (384x512): K=[asum|amax|x], Nout=[r_pre, z_pre, i_n, h_n].
// WcatF[k][j] = sum_t merge_W[k][t] * W_ih[j][t]  (merge folded into GRU input).
__global__ __launch_bounds__(256) void k_prep_gru(const float* __restrict__ merge_W,
        const float* __restrict__ W_ih, const float* __restrict__ W_hh,
        u16* __restrict__ Wp) {
    int tid = blockIdx.x * 256 + threadIdx.x;
    if (tid >= 384 * 512) return;
    int k = tid >> 9;          // 0..383
    int jout = tid & 511;      // 0..511
    float v = 0.f;
    if (jout < 256) {          // r,z: summed i+h contributions
        int j = jout;
        if (k < 256) {
            float acc = 0.f;
            for (int t = 0; t < DD; ++t) acc += merge_W[k * DD + t] * W_ih[j * DD + t];
            v = acc;
        } else v = W_hh[j * DD + (k - 256)];
    } else if (jout < 384) {   // i_n
        int j = jout;
        if (k < 256) {
            float acc = 0.f;
            for (int t = 0; t < DD; ++t) acc += merge_W[k * DD + t] * W_ih[j * DD + t];
            v = acc;
        }
    } else {                   // h_n
        int j = jout - 128;
        if (k >= 256) v = W_hh[j * DD + (k - 256)];
    }
    Wp[packB(k, jout, 12)] = f2bf(v);
}

__global__ __launch_bounds__(256) void k_prep_gru_bias(const float* __restrict__ merge_b,
        const float* __restrict__ W_ih,
        const float* __restrict__ b_ih, const float* __restrict__ b_hh,
        float* __restrict__ bg) {
    int jout = blockIdx.x * 256 + threadIdx.x;
    if (jout >= 512) return;
    float v;
    if (jout < 384) {
        int j = jout;
        float acc = b_ih[j];
        for (int t = 0; t < DD; ++t) acc += merge_b[t] * W_ih[j * DD + t];
        v = (jout < 256) ? acc + b_hh[j] : acc;
    } else {
        v = b_hh[jout - 128];
    }
    bg[jout] = v;
}

// W1 (128x256, row-major (k,j)) -> packed bf16 fragments, KT=4.
__global__ __launch_bounds__(256) void k_prep_w1(const float* __restrict__ W1,
                                                 u16* __restrict__ W1p) {
    int tid = blockIdx.x * 256 + threadIdx.x;
    if (tid >= DD * HH) return;
    int k = tid >> 8;
    int j = tid & 255;
    W1p[packB(k, j, 4)] = f2bf(W1[tid]);
}

// ---------------------------------------------------------------------------
// Fused GRU: U=[asum|amax|x] (bf16) @ W_gru + pointwise -> h (bf16).
// 32 rows/block, 4 waves; wave w owns n-tiles {g*8 + 2w + q} so all 4 gates
// of d-range [w*32, w*32+32) are wave-local.
__global__ __launch_bounds__(256) void k_gru(const u16* __restrict__ asum,
        const u16* __restrict__ amax, const u16* __restrict__ xb,
        const float* __restrict__ xf_g, const u16* __restrict__ Wp,
        const float* __restrict__ bg, u16* __restrict__ h_out) {
    __shared__ u16 U[32 * 392];     // 384 + 8 pad
    __shared__ float XF[32 * 132];  // 128 + 4 pad
    __shared__ u16 HS[32 * 136];    // 128 + 8 pad
    int t = threadIdx.x;
    int r0 = blockIdx.x * 32;
    int w = t >> 6, l = t & 63;

    #pragma unroll
    for (int src = 0; src < 3; ++src) {
        const u16* p = (src == 0) ? asum : (src == 1) ? amax : xb;
        #pragma unroll
        for (int it = 0; it < 2; ++it) {
            int i = t + it * 256;            // 512 chunks of 8 bf16
            int row = i >> 4, c = i & 15;
            uint4 v = make_uint4(0, 0, 0, 0);
            if (r0 + row < NN) v = *(const uint4*)(p + (size_t)(r0 + row) * DD + c * 8);
            *(uint4*)(&U[row * 392 + src * DD + c * 8]) = v;
        }
    }
    #pragma unroll
    for (int it = 0; it < 4; ++it) {
        int i = t + it * 256;                // 1024 float4
        int row = i >> 5, c = i & 31;
        float4 v = make_float4(0.f, 0.f, 0.f, 0.f);
        if (r0 + row < NN) v = ((const float4*)xf_g)[(size_t)(r0 + row) * 32 + c];
        *(float4*)(&XF[row * 132 + c * 4]) = v;
    }
    __syncthreads();

    f32x4 acc[2][4][2];
    #pragma unroll
    for (int mt = 0; mt < 2; ++mt)
        #pragma unroll
        for (int g = 0; g < 4; ++g)
            #pragma unroll
            for (int q = 0; q < 2; ++q) acc[mt][g][q] = (f32x4){0.f, 0.f, 0.f, 0.f};

    for (int kt = 0; kt < 12; ++kt) {
        bf16x8 a0 = *(const bf16x8*)(&U[((l & 15)) * 392 + kt * 32 + (l >> 4) * 8]);
        bf16x8 a1 = *(const bf16x8*)(&U[(16 + (l & 15)) * 392 + kt * 32 + (l >> 4) * 8]);
        #pragma unroll
        for (int g = 0; g < 4; ++g) {
            #pragma unroll
            for (int q = 0; q < 2; ++q) {
                int nt = g * 8 + 2 * w + q;
                bf16x8 b = *(const bf16x8*)(Wp + ((size_t)(nt * 12 + kt) * 64 + l) * 8);
                acc[0][g][q] = MFMA(a0, b, acc[0][g][q]);
                acc[1][g][q] = MFMA(a1, b, acc[1][g][q]);
            }
        }
    }

    #pragma unroll
    for (int mt = 0; mt < 2; ++mt) {
        #pragma unroll
        for (int q = 0; q < 2; ++q) {
            int dl = (2 * w + q) * 16 + (l & 15);     // 0..127
            float br = bg[dl], bz = bg[128 + dl], bi = bg[256 + dl], bh = bg[384 + dl];
            #pragma unroll
            for (int j = 0; j < 4; ++j) {
                int row = mt * 16 + (l >> 4) * 4 + j;
                float rp = acc[mt][0][q][j] + br;
                float zp = acc[mt][1][q][j] + bz;
                float ip = acc[mt][2][q][j] + bi;
                float hp = acc[mt][3][q][j] + bh;
                float r = 1.f / (1.f + __expf(-rp));
                float z = 1.f / (1.f + __expf(-zp));
                float n = tanhf(ip + r * hp);
                float xv = XF[row * 132 + dl];
                float h = (1.f - z) * n + z * xv;
                HS[row * 136 + dl] = f2bf(h);
            }
        }
    }
    __syncthreads();
    #pragma unroll
    for (int it = 0; it < 2; ++it) {
        int i = t + it * 256;
        int row = i >> 4, c = i & 15;
        if (r0 + row < NN)
            *(uint4*)(h_out + (size_t)(r0 + row) * DD + c * 8) = *(const uint4*)(&HS[row * 136 + c * 8]);
    }
}

// ---------------------------------------------------------------------------
// mlp1: s1 = leaky(h @ W1 + b1) (bf16 out) + column stats.
__global__ __launch_bounds__(256) void k_mlp1(const u16* __restrict__ h,
        const u16* __restrict__ W1p, const float* __restrict__ b1,
        u16* __restrict__ s1, float* __restrict__ sum1, float* __restrict__ sumsq1) {
    __shared__ u16 A[32 * 136];
    __shared__ u16 S[32 * 264];
    int t = threadIdx.x;
    int r0 = blockIdx.x * 32;
    int w = t >> 6, l = t & 63;

    #pragma unroll
    for (int it = 0; it < 2; ++it) {
        int i = t + it * 256;
        int row = i >> 4, c = i & 15;
        uint4 v = make_uint4(0, 0, 0, 0);
        if (r0 + row < NN) v = *(const uint4*)(h + (size_t)(r0 + row) * DD + c * 8);
        *(uint4*)(&A[row * 136 + c * 8]) = v;
    }
    __syncthreads();

    f32x4 acc[2][4];
    #pragma unroll
    for (int mt = 0; mt < 2; ++mt)
        #pragma unroll
        for (int nl = 0; nl < 4; ++nl) acc[mt][nl] = (f32x4){0.f, 0.f, 0.f, 0.f};

    for (int kt = 0; kt < 4; ++kt) {
        bf16x8 a0 = *(const bf16x8*)(&A[((l & 15)) * 136 + kt * 32 + (l >> 4) * 8]);
        bf16x8 a1 = *(const bf16x8*)(&A[(16 + (l & 15)) * 136 + kt * 32 + (l >> 4) * 8]);
        #pragma unroll
        for (int nl = 0; nl < 4; ++nl) {
            int nt = w * 4 + nl;
            bf16x8 b = *(const bf16x8*)(W1p + ((size_t)(nt * 4 + kt) * 64 + l) * 8);
            acc[0][nl] = MFMA(a0, b, acc[0][nl]);
            acc[1][nl] = MFMA(a1, b, acc[1][nl]);
        }
    }

    #pragma unroll
    for (int nl = 0; nl < 4; ++nl) {
        int dcol = (w * 4 + nl) * 16 + (l & 15);
        float bj = b1[dcol];
        float cs = 0.f, cq = 0.f;
        #pragma unroll
        for (int mt = 0; mt < 2; ++mt) {
            #pragma unroll
            for (int j = 0; j < 4; ++j) {
                int row = mt * 16 + (l >> 4) * 4 + j;
                float v = acc[mt][nl][j] + bj;
                v = (v >= 0.f) ? v : 0.01f * v;
                S[row * 264 + dcol] = f2bf(v);
                if (r0 + row < NN) { cs += v; cq += v * v; }
            }
        }
        cs += __shfl_xor(cs, 16); cs += __shfl_xor(cs, 32);
        cq += __shfl_xor(cq, 16); cq += __shfl_xor(cq, 32);
        if (l < 16) {
            atomicAdd(&sum1[dcol], cs);
            atomicAdd(&sumsq1[dcol], cq);
        }
    }
    __syncthreads();
    #pragma unroll
    for (int it = 0; it < 4; ++it) {
        int i = t + it * 256;                 // 1024 chunks
        int row = i >> 5, c = i & 31;
        if (r0 + row < NN)
            *(uint4*)(s1 + (size_t)(r0 + row) * HH + c * 8) = *(const uint4*)(&S[row * 264 + c * 8]);
    }
}

// BN1 fold into W2: W2p = a1*W2 (packed bf16), b2p = b2 + c1 @ W2.
__global__ __launch_bounds__(256) void k_prep2(const float* __restrict__ sum1,
        const float* __restrict__ sumsq1,
        const float* __restrict__ gamma1, const float* __restrict__ beta1,
        const float* __restrict__ W2, const float* __restrict__ b2,
        u16* __restrict__ W2p, float* __restrict__ b2p) {
    __shared__ float a1s[HH], c1s[HH];
    int t = threadIdx.x;
    {
        float m = sum1[t] * (1.f / NN);
        float var = sumsq1[t] * (1.f / NN) - m * m;
        float a = gamma1[t] * rsqrtf(var + BN_EPS);
        a1s[t] = a;
        c1s[t] = beta1[t] - a * m;
    }
    __syncthreads();
    if (blockIdx.x < 128) {
        int idx = blockIdx.x * 256 + t;       // 32768 elems
        int k = idx >> 7, j = idx & 127;
        W2p[packB(k, j, 8)] = f2bf(a1s[k] * W2[k * DD + j]);
    } else if (t < DD) {
        float acc = b2[t];
        for (int k = 0; k < HH; ++k) acc = fmaf(c1s[k], W2[k * DD + t], acc);
        b2p[t] = acc;
    }
}

// mlp2: s2 = leaky(s1 @ W2p + b2p) (f32 out) + column stats.
__global__ __launch_bounds__(256) void k_mlp2(const u16* __restrict__ s1,
        const u16* __restrict__ W2p, const float* __restrict__ b2p,
        float* __restrict__ s2, float* __restrict__ sum2, float* __restrict__ sumsq2) {
    __shared__ u16 A[32 * 264];
    int t = threadIdx.x;
    int r0 = blockIdx.x * 32;
    int w = t >> 6, l = t & 63;

    #pragma unroll
    for (int it = 0; it < 4; ++it) {
        int i = t + it * 256;
        int row = i >> 5, c = i & 31;
        uint4 v = make_uint4(0, 0, 0, 0);
        if (r0 + row < NN) v = *(const uint4*)(s1 + (size_t)(r0 + row) * HH + c * 8);
        *(uint4*)(&A[row * 264 + c * 8]) = v;
    }
    __syncthreads();

    f32x4 acc[2][2];
    #pragma unroll
    for (int mt = 0; mt < 2; ++mt)
        #pragma unroll
        for (int q = 0; q < 2; ++q) acc[mt][q] = (f32x4){0.f, 0.f, 0.f, 0.f};

    for (int kt = 0; kt < 8; ++kt) {
        bf16x8 a0 = *(const bf16x8*)(&A[((l & 15)) * 264 + kt * 32 + (l >> 4) * 8]);
        bf16x8 a1 = *(const bf16x8*)(&A[(16 + (l & 15)) * 264 + kt * 32 + (l >> 4) * 8]);
        #pragma unroll
        for (int q = 0; q < 2; ++q) {
            int nt = w * 2 + q;
            bf16x8 b = *(const bf16x8*)(W2p + ((size_t)(nt * 8 + kt) * 64 + l) * 8);
            acc[0][q] = MFMA(a0, b, acc[0][q]);
            acc[1][q] = MFMA(a1, b, acc[1][q]);
        }
    }

    #pragma unroll
    for (int q = 0; q < 2; ++q) {
        int dcol = (w * 2 + q) * 16 + (l & 15);
        float bj = b2p[dcol];
        float cs = 0.f, cq = 0.f;
        #pragma unroll
        for (int mt = 0; mt < 2; ++mt) {
            #pragma unroll
            for (int j = 0; j < 4; ++j) {
                int row = mt * 16 + (l >> 4) * 4 + j;
                float v = acc[mt][q][j] + bj;
                v = (v >= 0.f) ? v : 0.01f * v;
                if (r0 + row < NN) {
                    s2[(size_t)(r0 + row) * DD + dcol] = v;
                    cs += v; cq += v * v;
                }
            }
        }
        cs += __shfl_xor(cs, 16); cs += __shfl_xor(cs, 32);
        cq += __shfl_xor(cq, 16); cq += __shfl_xor(cq, 32);
        if (l < 16) {
            atomicAdd(&sum2[dcol], cs);
            atomicAdd(&sumsq2[dcol], cq);
        }
    }
}

__global__ __launch_bounds__(256) void k_bn_out(const float* __restrict__ s2,
        const float* __restrict__ sum2, const float* __restrict__ sumsq2,
        const float* __restrict__ gamma2, const float* __restrict__ beta2,
        float* __restrict__ out) {
    __shared__ float a2s[DD], c2s[DD];
    int t = threadIdx.x;
    if (t < DD) {
        float m = sum2[t] * (1.f / NN);
        float var = sumsq2[t] * (1.f / NN) - m * m;
        float a = gamma2[t] * rsqrtf(var + BN_EPS);
        a2s[t] = a;
        c2s[t] = beta2[t] - a * m;
    }
    __syncthreads();
    int tid = blockIdx.x * 256 + t;
    if (tid >= NN * DD / 4) return;
    int c4 = (tid & 31) * 4;
    float4 v = ((const float4*)s2)[tid];
    float4 o;
    o.x = a2s[c4 + 0] * v.x + c2s[c4 + 0];
    o.y = a2s[c4 + 1] * v.y + c2s[c4 + 1];
    o.z = a2s[c4 + 2] * v.z + c2s[c4 + 2];
    o.w = a2s[c4 + 3] * v.w + c2s[c4 + 3];
    ((float4*)out)[tid] = o;
}

// ---------------------------------------------------------------------------
extern "C" void kernel_launch(void* const* d_in, const int* in_sizes, int n_in,
                              void* d_out, int out_size, void* d_ws, size_t ws_size,
                              hipStream_t stream) {
    const float* x       = (const float*)d_in[0];
    const int*   edges   = (const int*)d_in[1];
    const float* merge_W = (const float*)d_in[2];
    const float* merge_b = (const float*)d_in[3];
    const float* W_ih    = (const float*)d_in[4];
    const float* W_hh    = (const float*)d_in[5];
    const float* b_ih    = (const float*)d_in[6];
    const float* b_hh    = (const float*)d_in[7];
    const float* W1      = (const float*)d_in[8];
    const float* b1      = (const float*)d_in[9];
    const float* gamma1  = (const float*)d_in[10];
    const float* beta1   = (const float*)d_in[11];
    const float* W2      = (const float*)d_in[12];
    const float* b2      = (const float*)d_in[13];
    const float* gamma2  = (const float*)d_in[14];
    const float* beta2   = (const float*)d_in[15];
    float* out = (float*)d_out;

    // ws layout (bytes):
    char* wsb = (char*)d_ws;
    u16*   xb     = (u16*)(wsb + 0);           // 12.8 MB, dead after k_gru
    u16*   asumb  = (u16*)(wsb + 12800000);    // 12.8 MB \ s2 (f32, 25.6MB)
    u16*   amaxb  = (u16*)(wsb + 25600000);    // 12.8 MB / overlays after k_gru
    u16*   hb     = (u16*)(wsb + 38400000);    // 12.8 MB
    u16*   s1b    = (u16*)(wsb + 51200000);    // 25.6 MB
    float* s2     = (float*)(wsb + 12800000);
    u16*   Wpg    = (u16*)(wsb + 76800000);    // 393,216 B
    u16*   W1p    = (u16*)(wsb + 77193216);    // 65,536 B
    u16*   W2p    = (u16*)(wsb + 77258752);    // 65,536 B
    float* bg     = (float*)(wsb + 77324288);  // 2,048 B
    float* b2p    = (float*)(wsb + 77326336);  // 512 B
    float* stats  = (float*)(wsb + 77326848);  // 3,072 B
    float* sum1   = stats;
    float* sumsq1 = stats + 256;
    float* sum2   = stats + 512;
    float* sumsq2 = stats + 640;
    int*   deg    = (int*)(wsb + 77329920);
    int*   rowptr = (int*)(wsb + 77529920);
    int*   cursor = (int*)(wsb + 77729924);
    int*   eidx   = (int*)(wsb + 77929924);
    // total ~80.3 MB

    const int NB = (NN + 31) / 32;   // 1563

    k_init<<<(NN + 255) / 256, 256, 0, stream>>>(deg, stats);
    k_count<<<(NE + 255) / 256, 256, 0, stream>>>(edges, deg);
    k_scan<<<1, 1024, 0, stream>>>(deg, rowptr, cursor);
    k_fill<<<(NE + 255) / 256, 256, 0, stream>>>(edges, cursor, eidx);
    k_xcast<<<(NN * DD / 8 + 255) / 256, 256, 0, stream>>>((const float4*)x, (uint4*)xb);
    k_prep_gru<<<(384 * 512 + 255) / 256, 256, 0, stream>>>(merge_W, W_ih, W_hh, Wpg);
    k_prep_gru_bias<<<2, 256, 0, stream>>>(merge_b, W_ih, b_ih, b_hh, bg);
    k_prep_w1<<<(DD * HH + 255) / 256, 256, 0, stream>>>(W1, W1p);
    k_aggregate<<<(NN * 64) / 256 + 1, 256, 0, stream>>>((const unsigned*)xb, rowptr, eidx,
                                                         (unsigned*)asumb, (unsigned*)amaxb);
    k_gru<<<NB, 256, 0, stream>>>(asumb, amaxb, xb, x, Wpg, bg, hb);
    k_mlp1<<<NB, 256, 0, stream>>>(hb, W1p, b1, s1b, sum1, sumsq1);
    k_prep2<<<129, 256, 0, stream>>>(sum1, sumsq1, gamma1, beta1, W2, b2, W2p, b2p);
    k_mlp2<<<NB, 256, 0, stream>>>(s1b, W2p, b2p, s2, sum2, sumsq2);
    k_bn_out<<<6250, 256, 0, stream>>>(s2, sum2, sumsq2, gamma2, beta2, out);
}

// Round 5
// 459.115 us; speedup vs baseline: 6.8593x; 1.2605x over previous
//
#include <hip/hip_runtime.h>
#include <hip/hip_bf16.h>
#include <math.h>

#define NN 50000
#define NE 600000
#define DD 128
#define HH 256
#define BN_EPS 1e-5f

typedef unsigned short u16;
typedef short bf16x8 __attribute__((ext_vector_type(8)));
typedef float f32x4 __attribute__((ext_vector_type(4)));

__device__ __forceinline__ u16 f2bf(float f) {
    unsigned int u = __float_as_uint(f);
    unsigned int r = (u + 0x7fffu + ((u >> 16) & 1u)) >> 16;
    return (u16)r;
}
__device__ __forceinline__ float bf2f(u16 b) {
    return __uint_as_float(((unsigned int)b) << 16);
}
#define MFMA(a, b, c) __builtin_amdgcn_mfma_f32_16x16x32_bf16((a), (b), (c), 0, 0, 0)

// ---------------------------------------------------------------------------
__global__ __launch_bounds__(256) void k_init(int* __restrict__ deg,
                                              float* __restrict__ stats) {
    int tid = blockIdx.x * 256 + threadIdx.x;
    if (tid < NN) deg[tid] = 0;
    if (tid < 768) stats[tid] = 0.f;
}

__global__ __launch_bounds__(256) void k_count(const int* __restrict__ edges,
                                               int* __restrict__ deg) {
    int e = blockIdx.x * 256 + threadIdx.x;
    if (e >= NE) return;
    atomicAdd(&deg[edges[NE + e]], 1);
}

// ---------------------------------------------------------------------------
// Hierarchical exclusive scan of deg[NN] (k_scan was 128us on 1 CU).
// scanA: per-block (512 elems) local scan; loc may ALIAS deg (each block
// reads its whole range before writing it). scanB: scan 98 block sums.
// scanC: add block offsets, emit rowptr + cursor.
__global__ __launch_bounds__(256) void k_scanA(const int* __restrict__ deg,
                                               int* __restrict__ loc,
                                               int* __restrict__ bsum) {
    __shared__ int s[256];
    int b = blockIdx.x, t = threadIdx.x;
    int i0 = b * 512 + t * 2;
    int d0 = (i0 < NN) ? deg[i0] : 0;
    int d1 = (i0 + 1 < NN) ? deg[i0 + 1] : 0;
    s[t] = d0 + d1;
    __syncthreads();
    for (int off = 1; off < 256; off <<= 1) {
        int v = (t >= off) ? s[t - off] : 0;
        __syncthreads();
        s[t] += v;
        __syncthreads();
    }
    int excl = (t > 0) ? s[t - 1] : 0;
    if (i0 < NN) loc[i0] = excl;
    if (i0 + 1 < NN) loc[i0 + 1] = excl + d0;
    if (t == 255) bsum[b] = s[255];
}

__global__ __launch_bounds__(128) void k_scanB(const int* __restrict__ bsum,
                                               int* __restrict__ boff) {
    __shared__ int s[128];
    int t = threadIdx.x;
    const int NBLK = (NN + 511) / 512;   // 98
    s[t] = (t < NBLK) ? bsum[t] : 0;
    __syncthreads();
    for (int off = 1; off < 128; off <<= 1) {
        int v = (t >= off) ? s[t - off] : 0;
        __syncthreads();
        s[t] += v;
        __syncthreads();
    }
    if (t < NBLK) boff[t] = (t > 0) ? s[t - 1] : 0;
}

__global__ __launch_bounds__(256) void k_scanC(const int* __restrict__ loc,
                                               const int* __restrict__ boff,
                                               int* __restrict__ rowptr,
                                               int* __restrict__ cursor) {
    int i = blockIdx.x * 256 + threadIdx.x;
    if (i < NN) {
        int v = loc[i] + boff[i >> 9];
        rowptr[i] = v;
        cursor[i] = v;
    }
    if (i == 0) rowptr[NN] = NE;   // total degree == edge count
}

__global__ __launch_bounds__(256) void k_fill(const int* __restrict__ edges,
                                              int* __restrict__ cursor,
                                              int* __restrict__ eidx) {
    int e = blockIdx.x * 256 + threadIdx.x;
    if (e >= NE) return;
    int src = edges[e];
    int dst = edges[NE + e];
    int slot = atomicAdd(&cursor[dst], 1);
    eidx[slot] = src;
}

// x f32 -> bf16 (8 elems/thread)
__global__ __launch_bounds__(256) void k_xcast(const float4* __restrict__ x4,
                                               uint4* __restrict__ xb4) {
    int tid = blockIdx.x * 256 + threadIdx.x;
    if (tid >= NN * DD / 8) return;
    float4 a = x4[tid * 2];
    float4 b = x4[tid * 2 + 1];
    uint4 o;
    o.x = (unsigned)f2bf(a.x) | ((unsigned)f2bf(a.y) << 16);
    o.y = (unsigned)f2bf(a.z) | ((unsigned)f2bf(a.w) << 16);
    o.z = (unsigned)f2bf(b.x) | ((unsigned)f2bf(b.y) << 16);
    o.w = (unsigned)f2bf(b.z) | ((unsigned)f2bf(b.w) << 16);
    xb4[tid] = o;
}

// ---------------------------------------------------------------------------
// One wave per node, 2 cols/lane (4B loads from bf16 x), f32 accumulate,
// bf16 store of agg_sum / agg_max.
__global__ __launch_bounds__(256) void k_aggregate(const unsigned* __restrict__ xb,
        const int* __restrict__ rowptr, const int* __restrict__ eidx,
        unsigned* __restrict__ asum, unsigned* __restrict__ amax) {
    int gid = blockIdx.x * 256 + threadIdx.x;
    int node = gid >> 6;
    int lane = threadIdx.x & 63;
    if (node >= NN) return;
    int beg = rowptr[node], end = rowptr[node + 1];
    float sx = 0.f, sy = 0.f;
    const float NINF = -__builtin_inff();
    float mx = NINF, my = NINF;
    for (int j = beg; j < end; ++j) {
        int src = eidx[j];
        unsigned v = xb[(size_t)src * 64 + lane];
        float vx = bf2f((u16)(v & 0xffff));
        float vy = bf2f((u16)(v >> 16));
        sx += vx; sy += vy;
        mx = fmaxf(mx, vx); my = fmaxf(my, vy);
    }
    if (beg == end) { mx = 0.f; my = 0.f; }
    asum[(size_t)node * 64 + lane] = (unsigned)f2bf(sx) | ((unsigned)f2bf(sy) << 16);
    amax[(size_t)node * 64 + lane] = (unsigned)f2bf(mx) | ((unsigned)f2bf(my) << 16);
}

// ---------------------------------------------------------------------------
// Pack helper: B-fragment layout for mfma_f32_16x16x32_bf16.
// lane l holds B[k=(l>>4)*8+e][n=l&15]; flat = ((nt*KT+kt)*64+l)*8+e.
__device__ __forceinline__ size_t packB(int k, int n, int KT) {
    int nt = n >> 4;
    int kt = k >> 5;
    int lane = (n & 15) | (((k >> 3) & 3) << 4);
    int e = k & 7;
    return ((size_t)(nt * KT + kt) * 64 + lane) * 8 + e;
}

// W_gru (384x512): K=[asum|amax|x], Nout=[r_pre, z_pre, i_n, h_n].
// WcatF[k][j] = sum_t merge_W[k][t] * W_ih[j][t]  (merge folded into GRU input).
__global__ __launch_bounds__(256) void k_prep_gru(const float* __restrict__ merge_W,
        const float* __restrict__ W_ih, const float* __restrict__ W_hh,
        u16* __restrict__ Wp) {
    int tid = blockIdx.x * 256 + threadIdx.x;
    if (tid >= 384 * 512) return;
    int k = tid >> 9;          // 0..383
    int jout = tid & 511;      // 0..511
    float v = 0.f;
    if (jout < 256) {          // r,z: summed i+h contributions
        int j = jout;
        if (k < 256) {
            float acc = 0.f;
            for (int t = 0; t < DD; ++t) acc += merge_W[k * DD + t] * W_ih[j * DD + t];
            v = acc;
        } else v = W_hh[j * DD + (k - 256)];
    } else if (jout < 384) {   // i_n
        int j = jout;
        if (k < 256) {
            float acc = 0.f;
            for (int t = 0; t < DD; ++t) acc += merge_W[k * DD + t] * W_ih[j * DD + t];
            v = acc;
        }
    } else {                   // h_n
        int j = jout - 128;
        if (k >= 256) v = W_hh[j * DD + (k - 256)];
    }
    Wp[packB(k, jout, 12)] = f2bf(v);
}

__global__ __launch_bounds__(256) void k_prep_gru_bias(const float* __restrict__ merge_b,
        const float* __restrict__ W_ih,
        const float* __restrict__ b_ih, const float* __restrict__ b_hh,
        float* __restrict__ bg) {
    int jout = blockIdx.x * 256 + threadIdx.x;
    if (jout >= 512) return;
    float v;
    if (jout < 384) {
        int j = jout;
        float acc = b_ih[j];
        for (int t = 0; t < DD; ++t) acc += merge_b[t] * W_ih[j * DD + t];
        v = (jout < 256) ? acc + b_hh[j] : acc;
    } else {
        v = b_hh[jout - 128];
    }
    bg[jout] = v;
}

// W1 (128x256, row-major (k,j)) -> packed bf16 fragments, KT=4.
__global__ __launch_bounds__(256) void k_prep_w1(const float* __restrict__ W1,
                                                 u16* __restrict__ W1p) {
    int tid = blockIdx.x * 256 + threadIdx.x;
    if (tid >= DD * HH) return;
    int k = tid >> 8;
    int j = tid & 255;
    W1p[packB(k, j, 4)] = f2bf(W1[tid]);
}

// ---------------------------------------------------------------------------
// Fused GRU: U=[asum|amax|x] (bf16) @ W_gru + pointwise -> h (bf16).
// 32 rows/block, 4 waves; wave w owns n-tiles {g*8 + 2w + q} so all 4 gates
// of d-range [w*32, w*32+32) are wave-local.
__global__ __launch_bounds__(256) void k_gru(const u16* __restrict__ asum,
        const u16* __restrict__ amax, const u16* __restrict__ xb,
        const float* __restrict__ xf_g, const u16* __restrict__ Wp,
        const float* __restrict__ bg, u16* __restrict__ h_out) {
    __shared__ u16 U[32 * 392];     // 384 + 8 pad
    __shared__ float XF[32 * 132];  // 128 + 4 pad
    __shared__ u16 HS[32 * 136];    // 128 + 8 pad
    int t = threadIdx.x;
    int r0 = blockIdx.x * 32;
    int w = t >> 6, l = t & 63;

    #pragma unroll
    for (int src = 0; src < 3; ++src) {
        const u16* p = (src == 0) ? asum : (src == 1) ? amax : xb;
        #pragma unroll
        for (int it = 0; it < 2; ++it) {
            int i = t + it * 256;            // 512 chunks of 8 bf16
            int row = i >> 4, c = i & 15;
            uint4 v = make_uint4(0, 0, 0, 0);
            if (r0 + row < NN) v = *(const uint4*)(p + (size_t)(r0 + row) * DD + c * 8);
            *(uint4*)(&U[row * 392 + src * DD + c * 8]) = v;
        }
    }
    #pragma unroll
    for (int it = 0; it < 4; ++it) {
        int i = t + it * 256;                // 1024 float4
        int row = i >> 5, c = i & 31;
        float4 v = make_float4(0.f, 0.f, 0.f, 0.f);
        if (r0 + row < NN) v = ((const float4*)xf_g)[(size_t)(r0 + row) * 32 + c];
        *(float4*)(&XF[row * 132 + c * 4]) = v;
    }
    __syncthreads();

    f32x4 acc[2][4][2];
    #pragma unroll
    for (int mt = 0; mt < 2; ++mt)
        #pragma unroll
        for (int g = 0; g < 4; ++g)
            #pragma unroll
            for (int q = 0; q < 2; ++q) acc[mt][g][q] = (f32x4){0.f, 0.f, 0.f, 0.f};

    for (int kt = 0; kt < 12; ++kt) {
        bf16x8 a0 = *(const bf16x8*)(&U[((l & 15)) * 392 + kt * 32 + (l >> 4) * 8]);
        bf16x8 a1 = *(const bf16x8*)(&U[(16 + (l & 15)) * 392 + kt * 32 + (l >> 4) * 8]);
        #pragma unroll
        for (int g = 0; g < 4; ++g) {
            #pragma unroll
            for (int q = 0; q < 2; ++q) {
                int nt = g * 8 + 2 * w + q;
                bf16x8 b = *(const bf16x8*)(Wp + ((size_t)(nt * 12 + kt) * 64 + l) * 8);
                acc[0][g][q] = MFMA(a0, b, acc[0][g][q]);
                acc[1][g][q] = MFMA(a1, b, acc[1][g][q]);
            }
        }
    }

    #pragma unroll
    for (int mt = 0; mt < 2; ++mt) {
        #pragma unroll
        for (int q = 0; q < 2; ++q) {
            int dl = (2 * w + q) * 16 + (l & 15);     // 0..127
            float br = bg[dl], bz = bg[128 + dl], bi = bg[256 + dl], bh = bg[384 + dl];
            #pragma unroll
            for (int j = 0; j < 4; ++j) {
                int row = mt * 16 + (l >> 4) * 4 + j;
                float rp = acc[mt][0][q][j] + br;
                float zp = acc[mt][1][q][j] + bz;
                float ip = acc[mt][2][q][j] + bi;
                float hp = acc[mt][3][q][j] + bh;
                float r = 1.f / (1.f + __expf(-rp));
                float z = 1.f / (1.f + __expf(-zp));
                float n = tanhf(ip + r * hp);
                float xv = XF[row * 132 + dl];
                float h = (1.f - z) * n + z * xv;
                HS[row * 136 + dl] = f2bf(h);
            }
        }
    }
    __syncthreads();
    #pragma unroll
    for (int it = 0; it < 2; ++it) {
        int i = t + it * 256;
        int row = i >> 4, c = i & 15;
        if (r0 + row < NN)
            *(uint4*)(h_out + (size_t)(r0 + row) * DD + c * 8) = *(const uint4*)(&HS[row * 136 + c * 8]);
    }
}

// ---------------------------------------------------------------------------
// mlp1: s1 = leaky(h @ W1 + b1) (bf16 out) + column stats.
__global__ __launch_bounds__(256) void k_mlp1(const u16* __restrict__ h,
        const u16* __restrict__ W1p, const float* __restrict__ b1,
        u16* __restrict__ s1, float* __restrict__ sum1, float* __restrict__ sumsq1) {
    __shared__ u16 A[32 * 136];
    __shared__ u16 S[32 * 264];
    int t = threadIdx.x;
    int r0 = blockIdx.x * 32;
    int w = t >> 6, l = t & 63;

    #pragma unroll
    for (int it = 0; it < 2; ++it) {
        int i = t + it * 256;
        int row = i >> 4, c = i & 15;
        uint4 v = make_uint4(0, 0, 0, 0);
        if (r0 + row < NN) v = *(const uint4*)(h + (size_t)(r0 + row) * DD + c * 8);
        *(uint4*)(&A[row * 136 + c * 8]) = v;
    }
    __syncthreads();

    f32x4 acc[2][4];
    #pragma unroll
    for (int mt = 0; mt < 2; ++mt)
        #pragma unroll
        for (int nl = 0; nl < 4; ++nl) acc[mt][nl] = (f32x4){0.f, 0.f, 0.f, 0.f};

    for (int kt = 0; kt < 4; ++kt) {
        bf16x8 a0 = *(const bf16x8*)(&A[((l & 15)) * 136 + kt * 32 + (l >> 4) * 8]);
        bf16x8 a1 = *(const bf16x8*)(&A[(16 + (l & 15)) * 136 + kt * 32 + (l >> 4) * 8]);
        #pragma unroll
        for (int nl = 0; nl < 4; ++nl) {
            int nt = w * 4 + nl;
            bf16x8 b = *(const bf16x8*)(W1p + ((size_t)(nt * 4 + kt) * 64 + l) * 8);
            acc[0][nl] = MFMA(a0, b, acc[0][nl]);
            acc[1][nl] = MFMA(a1, b, acc[1][nl]);
        }
    }

    #pragma unroll
    for (int nl = 0; nl < 4; ++nl) {
        int dcol = (w * 4 + nl) * 16 + (l & 15);
        float bj = b1[dcol];
        float cs = 0.f, cq = 0.f;
        #pragma unroll
        for (int mt = 0; mt < 2; ++mt) {
            #pragma unroll
            for (int j = 0; j < 4; ++j) {
                int row = mt * 16 + (l >> 4) * 4 + j;
                float v = acc[mt][nl][j] + bj;
                v = (v >= 0.f) ? v : 0.01f * v;
                S[row * 264 + dcol] = f2bf(v);
                if (r0 + row < NN) { cs += v; cq += v * v; }
            }
        }
        cs += __shfl_xor(cs, 16); cs += __shfl_xor(cs, 32);
        cq += __shfl_xor(cq, 16); cq += __shfl_xor(cq, 32);
        if (l < 16) {
            atomicAdd(&sum1[dcol], cs);
            atomicAdd(&sumsq1[dcol], cq);
        }
    }
    __syncthreads();
    #pragma unroll
    for (int it = 0; it < 4; ++it) {
        int i = t + it * 256;                 // 1024 chunks
        int row = i >> 5, c = i & 31;
        if (r0 + row < NN)
            *(uint4*)(s1 + (size_t)(r0 + row) * HH + c * 8) = *(const uint4*)(&S[row * 264 + c * 8]);
    }
}

// BN1 fold into W2: W2p = a1*W2 (packed bf16), b2p = b2 + c1 @ W2.
__global__ __launch_bounds__(256) void k_prep2(const float* __restrict__ sum1,
        const float* __restrict__ sumsq1,
        const float* __restrict__ gamma1, const float* __restrict__ beta1,
        const float* __restrict__ W2, const float* __restrict__ b2,
        u16* __restrict__ W2p, float* __restrict__ b2p) {
    __shared__ float a1s[HH], c1s[HH];
    int t = threadIdx.x;
    {
        float m = sum1[t] * (1.f / NN);
        float var = sumsq1[t] * (1.f / NN) - m * m;
        float a = gamma1[t] * rsqrtf(var + BN_EPS);
        a1s[t] = a;
        c1s[t] = beta1[t] - a * m;
    }
    __syncthreads();
    if (blockIdx.x < 128) {
        int idx = blockIdx.x * 256 + t;       // 32768 elems
        int k = idx >> 7, j = idx & 127;
        W2p[packB(k, j, 8)] = f2bf(a1s[k] * W2[k * DD + j]);
    } else if (t < DD) {
        float acc = b2[t];
        for (int k = 0; k < HH; ++k) acc = fmaf(c1s[k], W2[k * DD + t], acc);
        b2p[t] = acc;
    }
}

// mlp2: s2 = leaky(s1 @ W2p + b2p) (f32 out) + column stats.
__global__ __launch_bounds__(256) void k_mlp2(const u16* __restrict__ s1,
        const u16* __restrict__ W2p, const float* __restrict__ b2p,
        float* __restrict__ s2, float* __restrict__ sum2, float* __restrict__ sumsq2) {
    __shared__ u16 A[32 * 264];
    int t = threadIdx.x;
    int r0 = blockIdx.x * 32;
    int w = t >> 6, l = t & 63;

    #pragma unroll
    for (int it = 0; it < 4; ++it) {
        int i = t + it * 256;
        int row = i >> 5, c = i & 31;
        uint4 v = make_uint4(0, 0, 0, 0);
        if (r0 + row < NN) v = *(const uint4*)(s1 + (size_t)(r0 + row) * HH + c * 8);
        *(uint4*)(&A[row * 264 + c * 8]) = v;
    }
    __syncthreads();

    f32x4 acc[2][2];
    #pragma unroll
    for (int mt = 0; mt < 2; ++mt)
        #pragma unroll
        for (int q = 0; q < 2; ++q) acc[mt][q] = (f32x4){0.f, 0.f, 0.f, 0.f};

    for (int kt = 0; kt < 8; ++kt) {
        bf16x8 a0 = *(const bf16x8*)(&A[((l & 15)) * 264 + kt * 32 + (l >> 4) * 8]);
        bf16x8 a1 = *(const bf16x8*)(&A[(16 + (l & 15)) * 264 + kt * 32 + (l >> 4) * 8]);
        #pragma unroll
        for (int q = 0; q < 2; ++q) {
            int nt = w * 2 + q;
            bf16x8 b = *(const bf16x8*)(W2p + ((size_t)(nt * 8 + kt) * 64 + l) * 8);
            acc[0][q] = MFMA(a0, b, acc[0][q]);
            acc[1][q] = MFMA(a1, b, acc[1][q]);
        }
    }

    #pragma unroll
    for (int q = 0; q < 2; ++q) {
        int dcol = (w * 2 + q) * 16 + (l & 15);
        float bj = b2p[dcol];
        float cs = 0.f, cq = 0.f;
        #pragma unroll
        for (int mt = 0; mt < 2; ++mt) {
            #pragma unroll
            for (int j = 0; j < 4; ++j) {
                int row = mt * 16 + (l >> 4) * 4 + j;
                float v = acc[mt][q][j] + bj;
                v = (v >= 0.f) ? v : 0.01f * v;
                if (r0 + row < NN) {
                    s2[(size_t)(r0 + row) * DD + dcol] = v;
                    cs += v; cq += v * v;
                }
            }
        }
        cs += __shfl_xor(cs, 16); cs += __shfl_xor(cs, 32);
        cq += __shfl_xor(cq, 16); cq += __shfl_xor(cq, 32);
        if (l < 16) {
            atomicAdd(&sum2[dcol], cs);
            atomicAdd(&sumsq2[dcol], cq);
        }
    }
}

__global__ __launch_bounds__(256) void k_bn_out(const float* __restrict__ s2,
        const float* __restrict__ sum2, const float* __restrict__ sumsq2,
        const float* __restrict__ gamma2, const float* __restrict__ beta2,
        float* __restrict__ out) {
    __shared__ float a2s[DD], c2s[DD];
    int t = threadIdx.x;
    if (t < DD) {
        float m = sum2[t] * (1.f / NN);
        float var = sumsq2[t] * (1.f / NN) - m * m;
        float a = gamma2[t] * rsqrtf(var + BN_EPS);
        a2s[t] = a;
        c2s[t] = beta2[t] - a * m;
    }
    __syncthreads();
    int tid = blockIdx.x * 256 + t;
    if (tid >= NN * DD / 4) return;
    int c4 = (tid & 31) * 4;
    float4 v = ((const float4*)s2)[tid];
    float4 o;
    o.x = a2s[c4 + 0] * v.x + c2s[c4 + 0];
    o.y = a2s[c4 + 1] * v.y + c2s[c4 + 1];
    o.z = a2s[c4 + 2] * v.z + c2s[c4 + 2];
    o.w = a2s[c4 + 3] * v.w + c2s[c4 + 3];
    ((float4*)out)[tid] = o;
}

// ---------------------------------------------------------------------------
extern "C" void kernel_launch(void* const* d_in, const int* in_sizes, int n_in,
                              void* d_out, int out_size, void* d_ws, size_t ws_size,
                              hipStream_t stream) {
    const float* x       = (const float*)d_in[0];
    const int*   edges   = (const int*)d_in[1];
    const float* merge_W = (const float*)d_in[2];
    const float* merge_b = (const float*)d_in[3];
    const float* W_ih    = (const float*)d_in[4];
    const float* W_hh    = (const float*)d_in[5];
    const float* b_ih    = (const float*)d_in[6];
    const float* b_hh    = (const float*)d_in[7];
    const float* W1      = (const float*)d_in[8];
    const float* b1      = (const float*)d_in[9];
    const float* gamma1  = (const float*)d_in[10];
    const float* beta1   = (const float*)d_in[11];
    const float* W2      = (const float*)d_in[12];
    const float* b2      = (const float*)d_in[13];
    const float* gamma2  = (const float*)d_in[14];
    const float* beta2   = (const float*)d_in[15];
    float* out = (float*)d_out;

    // ws layout (bytes):
    char* wsb = (char*)d_ws;
    u16*   xb     = (u16*)(wsb + 0);           // 12.8 MB, dead after k_gru
    u16*   asumb  = (u16*)(wsb + 12800000);    // 12.8 MB \ s2 (f32, 25.6MB)
    u16*   amaxb  = (u16*)(wsb + 25600000);    // 12.8 MB / overlays after k_gru
    u16*   hb     = (u16*)(wsb + 38400000);    // 12.8 MB
    u16*   s1b    = (u16*)(wsb + 51200000);    // 25.6 MB
    float* s2     = (float*)(wsb + 12800000);
    u16*   Wpg    = (u16*)(wsb + 76800000);    // 393,216 B
    u16*   W1p    = (u16*)(wsb + 77193216);    // 65,536 B
    u16*   W2p    = (u16*)(wsb + 77258752);    // 65,536 B
    float* bg     = (float*)(wsb + 77324288);  // 2,048 B
    float* b2p    = (float*)(wsb + 77326336);  // 512 B
    float* stats  = (float*)(wsb + 77326848);  // 3,072 B
    float* sum1   = stats;
    float* sumsq1 = stats + 256;
    float* sum2   = stats + 512;
    float* sumsq2 = stats + 640;
    int*   deg    = (int*)(wsb + 77329920);    // 50,000 ints (loc aliases deg)
    int*   rowptr = (int*)(wsb + 77529920);    // 50,001 ints
    int*   cursor = (int*)(wsb + 77729924);    // 50,000 ints
    int*   eidx   = (int*)(wsb + 77929924);    // 600,000 ints
    int*   bsum   = (int*)(wsb + 80329924);    // 98 ints
    int*   boff   = (int*)(wsb + 80330316);    // 98 ints
    // total ~80.33 MB

    const int NB = (NN + 31) / 32;        // 1563
    const int NBLK = (NN + 511) / 512;    // 98

    k_init<<<(NN + 255) / 256, 256, 0, stream>>>(deg, stats);
    k_count<<<(NE + 255) / 256, 256, 0, stream>>>(edges, deg);
    k_scanA<<<NBLK, 256, 0, stream>>>(deg, deg, bsum);      // loc aliases deg (safe)
    k_scanB<<<1, 128, 0, stream>>>(bsum, boff);
    k_scanC<<<(NN + 255) / 256, 256, 0, stream>>>(deg, boff, rowptr, cursor);
    k_fill<<<(NE + 255) / 256, 256, 0, stream>>>(edges, cursor, eidx);
    k_xcast<<<(NN * DD / 8 + 255) / 256, 256, 0, stream>>>((const float4*)x, (uint4*)xb);
    k_prep_gru<<<(384 * 512 + 255) / 256, 256, 0, stream>>>(merge_W, W_ih, W_hh, Wpg);
    k_prep_gru_bias<<<2, 256, 0, stream>>>(merge_b, W_ih, b_ih, b_hh, bg);
    k_prep_w1<<<(DD * HH + 255) / 256, 256, 0, stream>>>(W1, W1p);
    k_aggregate<<<(NN * 64) / 256 + 1, 256, 0, stream>>>((const unsigned*)xb, rowptr, eidx,
                                                         (unsigned*)asumb, (unsigned*)amaxb);
    k_gru<<<NB, 256, 0, stream>>>(asumb, amaxb, xb, x, Wpg, bg, hb);
    k_mlp1<<<NB, 256, 0, stream>>>(hb, W1p, b1, s1b, sum1, sumsq1);
    k_prep2<<<129, 256, 0, stream>>>(sum1, sumsq1, gamma1, beta1, W2, b2, W2p, b2p);
    k_mlp2<<<NB, 256, 0, stream>>>(s1b, W2p, b2p, s2, sum2, sumsq2);
    k_bn_out<<<6250, 256, 0, stream>>>(s2, sum2, sumsq2, gamma2, beta2, out);
}

// Round 8
// 399.720 us; speedup vs baseline: 7.8786x; 1.1486x over previous
//
#include <hip/hip_runtime.h>
#include <hip/hip_bf16.h>
#include <math.h>

#define NN 50000
#define NE 600000
#define DD 128
#define HH 256
#define BN_EPS 1e-5f

typedef unsigned short u16;
typedef short bf16x8 __attribute__((ext_vector_type(8)));
typedef float f32x4 __attribute__((ext_vector_type(4)));

__device__ __forceinline__ u16 f2bf(float f) {
    unsigned int u = __float_as_uint(f);
    unsigned int r = (u + 0x7fffu + ((u >> 16) & 1u)) >> 16;
    return (u16)r;
}
__device__ __forceinline__ float bf2f(u16 b) {
    return __uint_as_float(((unsigned int)b) << 16);
}
#define MFMA(a, b, c) __builtin_amdgcn_mfma_f32_16x16x32_bf16((a), (b), (c), 0, 0, 0)

// ---------------------------------------------------------------------------
__global__ __launch_bounds__(256) void k_init(int* __restrict__ deg,
                                              float* __restrict__ stats) {
    int tid = blockIdx.x * 256 + threadIdx.x;
    if (tid < NN) deg[tid] = 0;
    if (tid < 768) stats[tid] = 0.f;
}

__global__ __launch_bounds__(256) void k_count(const int* __restrict__ edges,
                                               int* __restrict__ deg) {
    int e = blockIdx.x * 256 + threadIdx.x;
    if (e >= NE) return;
    atomicAdd(&deg[edges[NE + e]], 1);
}

// Hierarchical exclusive scan of deg[NN].
__global__ __launch_bounds__(256) void k_scanA(const int* __restrict__ deg,
                                               int* __restrict__ loc,
                                               int* __restrict__ bsum) {
    __shared__ int s[256];
    int b = blockIdx.x, t = threadIdx.x;
    int i0 = b * 512 + t * 2;
    int d0 = (i0 < NN) ? deg[i0] : 0;
    int d1 = (i0 + 1 < NN) ? deg[i0 + 1] : 0;
    s[t] = d0 + d1;
    __syncthreads();
    for (int off = 1; off < 256; off <<= 1) {
        int v = (t >= off) ? s[t - off] : 0;
        __syncthreads();
        s[t] += v;
        __syncthreads();
    }
    int excl = (t > 0) ? s[t - 1] : 0;
    if (i0 < NN) loc[i0] = excl;
    if (i0 + 1 < NN) loc[i0 + 1] = excl + d0;
    if (t == 255) bsum[b] = s[255];
}

__global__ __launch_bounds__(128) void k_scanB(const int* __restrict__ bsum,
                                               int* __restrict__ boff) {
    __shared__ int s[128];
    int t = threadIdx.x;
    const int NBLK = (NN + 511) / 512;   // 98
    s[t] = (t < NBLK) ? bsum[t] : 0;
    __syncthreads();
    for (int off = 1; off < 128; off <<= 1) {
        int v = (t >= off) ? s[t - off] : 0;
        __syncthreads();
        s[t] += v;
        __syncthreads();
    }
    if (t < NBLK) boff[t] = (t > 0) ? s[t - 1] : 0;
}

__global__ __launch_bounds__(256) void k_scanC(const int* __restrict__ loc,
                                               const int* __restrict__ boff,
                                               int* __restrict__ rowptr,
                                               int* __restrict__ cursor) {
    int i = blockIdx.x * 256 + threadIdx.x;
    if (i < NN) {
        int v = loc[i] + boff[i >> 9];
        rowptr[i] = v;
        cursor[i] = v;
    }
    if (i == 0) rowptr[NN] = NE;
}

__global__ __launch_bounds__(256) void k_fill(const int* __restrict__ edges,
                                              int* __restrict__ cursor,
                                              int* __restrict__ eidx) {
    int e = blockIdx.x * 256 + threadIdx.x;
    if (e >= NE) return;
    int src = edges[e];
    int dst = edges[NE + e];
    int slot = atomicAdd(&cursor[dst], 1);
    eidx[slot] = src;
}

// x f32 -> bf16 (8 elems/thread)
__global__ __launch_bounds__(256) void k_xcast(const float4* __restrict__ x4,
                                               uint4* __restrict__ xb4) {
    int tid = blockIdx.x * 256 + threadIdx.x;
    if (tid >= NN * DD / 8) return;
    float4 a = x4[tid * 2];
    float4 b = x4[tid * 2 + 1];
    uint4 o;
    o.x = (unsigned)f2bf(a.x) | ((unsigned)f2bf(a.y) << 16);
    o.y = (unsigned)f2bf(a.z) | ((unsigned)f2bf(a.w) << 16);
    o.z = (unsigned)f2bf(b.x) | ((unsigned)f2bf(b.y) << 16);
    o.w = (unsigned)f2bf(b.z) | ((unsigned)f2bf(b.w) << 16);
    xb4[tid] = o;
}

// ---------------------------------------------------------------------------
// One wave per node; 4-way unrolled gather for memory-level parallelism.
__global__ __launch_bounds__(256) void k_aggregate(const unsigned* __restrict__ xb,
        const int* __restrict__ rowptr, const int* __restrict__ eidx,
        unsigned* __restrict__ asum, unsigned* __restrict__ amax) {
    int gid = blockIdx.x * 256 + threadIdx.x;
    int node = gid >> 6;
    int lane = threadIdx.x & 63;
    if (node >= NN) return;
    int beg = rowptr[node], end = rowptr[node + 1];
    float sx = 0.f, sy = 0.f;
    const float NINF = -__builtin_inff();
    float mx = NINF, my = NINF;
    int j = beg;
    for (; j + 4 <= end; j += 4) {
        int i0 = eidx[j], i1 = eidx[j + 1], i2 = eidx[j + 2], i3 = eidx[j + 3];
        unsigned v0 = xb[(size_t)i0 * 64 + lane];
        unsigned v1 = xb[(size_t)i1 * 64 + lane];
        unsigned v2 = xb[(size_t)i2 * 64 + lane];
        unsigned v3 = xb[(size_t)i3 * 64 + lane];
        float a0 = bf2f((u16)(v0 & 0xffff)), b0 = bf2f((u16)(v0 >> 16));
        float a1 = bf2f((u16)(v1 & 0xffff)), b1 = bf2f((u16)(v1 >> 16));
        float a2 = bf2f((u16)(v2 & 0xffff)), b2 = bf2f((u16)(v2 >> 16));
        float a3 = bf2f((u16)(v3 & 0xffff)), b3 = bf2f((u16)(v3 >> 16));
        sx += a0 + a1 + a2 + a3;
        sy += b0 + b1 + b2 + b3;
        mx = fmaxf(fmaxf(fmaxf(mx, a0), fmaxf(a1, a2)), a3);
        my = fmaxf(fmaxf(fmaxf(my, b0), fmaxf(b1, b2)), b3);
    }
    for (; j < end; ++j) {
        int src = eidx[j];
        unsigned v = xb[(size_t)src * 64 + lane];
        float vx = bf2f((u16)(v & 0xffff));
        float vy = bf2f((u16)(v >> 16));
        sx += vx; sy += vy;
        mx = fmaxf(mx, vx); my = fmaxf(my, vy);
    }
    if (beg == end) { mx = 0.f; my = 0.f; }
    asum[(size_t)node * 64 + lane] = (unsigned)f2bf(sx) | ((unsigned)f2bf(sy) << 16);
    amax[(size_t)node * 64 + lane] = (unsigned)f2bf(mx) | ((unsigned)f2bf(my) << 16);
}

// ---------------------------------------------------------------------------
// Pack helper: B-fragment layout for mfma_f32_16x16x32_bf16.
// lane l holds B[k=(l>>4)*8+e][n=l&15]; flat = ((nt*KT+kt)*64+l)*8+e.
__device__ __forceinline__ size_t packB(int k, int n, int KT) {
    int nt = n >> 4;
    int kt = k >> 5;
    int lane = (n & 15) | (((k >> 3) & 3) << 4);
    int e = k & 7;
    return ((size_t)(nt * KT + kt) * 64 + lane) * 8 + e;
}

// Merged weight prep: blocks [0,768) -> W_gru pack; [768,770) -> gru bias;
// [770,898) -> W1 pack.
__global__ __launch_bounds__(256) void k_prep_w(const float* __restrict__ merge_W,
        const float* __restrict__ W_ih, const float* __restrict__ W_hh,
        const float* __restrict__ merge_b,
        const float* __restrict__ b_ih, const float* __restrict__ b_hh,
        const float* __restrict__ W1,
        u16* __restrict__ Wp, float* __restrict__ bg, u16* __restrict__ W1p) {
    int bid = blockIdx.x, t = threadIdx.x;
    if (bid < 768) {
        int tid = bid * 256 + t;               // 0 .. 384*512
        int k = tid >> 9;
        int jout = tid & 511;
        float v = 0.f;
        if (jout < 256) {          // r,z: summed i+h contributions
            int j = jout;
            if (k < 256) {
                float acc = 0.f;
                for (int q = 0; q < DD; ++q) acc += merge_W[k * DD + q] * W_ih[j * DD + q];
                v = acc;
            } else v = W_hh[j * DD + (k - 256)];
        } else if (jout < 384) {   // i_n
            int j = jout;
            if (k < 256) {
                float acc = 0.f;
                for (int q = 0; q < DD; ++q) acc += merge_W[k * DD + q] * W_ih[j * DD + q];
                v = acc;
            }
        } else {                   // h_n
            int j = jout - 128;
            if (k >= 256) v = W_hh[j * DD + (k - 256)];
        }
        Wp[packB(k, jout, 12)] = f2bf(v);
    } else if (bid < 770) {
        int jout = (bid - 768) * 256 + t;      // 0..512
        float v;
        if (jout < 384) {
            int j = jout;
            float acc = b_ih[j];
            for (int q = 0; q < DD; ++q) acc += merge_b[q] * W_ih[j * DD + q];
            v = (jout < 256) ? acc + b_hh[j] : acc;
        } else {
            v = b_hh[jout - 128];
        }
        bg[jout] = v;
    } else {
        int tid = (bid - 770) * 256 + t;       // 0 .. 128*256
        int k = tid >> 8;
        int j = tid & 255;
        W1p[packB(k, j, 4)] = f2bf(W1[tid]);
    }
}

// ---------------------------------------------------------------------------
// Fused GRU + MLP1. Phase 1: U=[asum|amax|x]@W_gru + GRU pointwise -> HS (LDS
// only, h never hits global). Phase 2: s1 = leaky(HS @ W1 + b1) + col stats.
// 32 rows/block, 4 waves. LDS = 33.8KB -> 4 blocks/CU.
__global__ __launch_bounds__(256) void k_gru_mlp1(const u16* __restrict__ asum,
        const u16* __restrict__ amax, const u16* __restrict__ xb,
        const u16* __restrict__ Wp, const float* __restrict__ bg,
        const u16* __restrict__ W1p, const float* __restrict__ b1,
        u16* __restrict__ s1, float* __restrict__ sum1, float* __restrict__ sumsq1) {
    __shared__ u16 U[32 * 392];     // 384 + 8 pad
    __shared__ u16 HS[32 * 136];    // 128 + 8 pad
    int t = threadIdx.x;
    int r0 = blockIdx.x * 32;
    int w = t >> 6, l = t & 63;

    #pragma unroll
    for (int src = 0; src < 3; ++src) {
        const u16* p = (src == 0) ? asum : (src == 1) ? amax : xb;
        #pragma unroll
        for (int it = 0; it < 2; ++it) {
            int i = t + it * 256;            // 512 chunks of 8 bf16
            int row = i >> 4, c = i & 15;
            uint4 v = make_uint4(0, 0, 0, 0);
            if (r0 + row < NN) v = *(const uint4*)(p + (size_t)(r0 + row) * DD + c * 8);
            *(uint4*)(&U[row * 392 + src * DD + c * 8]) = v;
        }
    }
    __syncthreads();

    // ---- Phase 1: GRU GEMM (K=384, Nout=512) ----
    {
        f32x4 acc[2][4][2];
        #pragma unroll
        for (int mt = 0; mt < 2; ++mt)
            #pragma unroll
            for (int g = 0; g < 4; ++g)
                #pragma unroll
                for (int q = 0; q < 2; ++q) acc[mt][g][q] = (f32x4){0.f, 0.f, 0.f, 0.f};

        for (int kt = 0; kt < 12; ++kt) {
            bf16x8 a0 = *(const bf16x8*)(&U[((l & 15)) * 392 + kt * 32 + (l >> 4) * 8]);
            bf16x8 a1 = *(const bf16x8*)(&U[(16 + (l & 15)) * 392 + kt * 32 + (l >> 4) * 8]);
            #pragma unroll
            for (int g = 0; g < 4; ++g) {
                #pragma unroll
                for (int q = 0; q < 2; ++q) {
                    int nt = g * 8 + 2 * w + q;
                    bf16x8 b = *(const bf16x8*)(Wp + ((size_t)(nt * 12 + kt) * 64 + l) * 8);
                    acc[0][g][q] = MFMA(a0, b, acc[0][g][q]);
                    acc[1][g][q] = MFMA(a1, b, acc[1][g][q]);
                }
            }
        }

        #pragma unroll
        for (int mt = 0; mt < 2; ++mt) {
            #pragma unroll
            for (int q = 0; q < 2; ++q) {
                int dl = (2 * w + q) * 16 + (l & 15);     // 0..127
                float br = bg[dl], bz = bg[128 + dl], bi = bg[256 + dl], bh = bg[384 + dl];
                #pragma unroll
                for (int j = 0; j < 4; ++j) {
                    int row = mt * 16 + (l >> 4) * 4 + j;
                    float rp = acc[mt][0][q][j] + br;
                    float zp = acc[mt][1][q][j] + bz;
                    float ip = acc[mt][2][q][j] + bi;
                    float hp = acc[mt][3][q][j] + bh;
                    float r = 1.f / (1.f + __expf(-rp));
                    float z = 1.f / (1.f + __expf(-zp));
                    float n = tanhf(ip + r * hp);
                    float xv = bf2f(U[row * 392 + 2 * DD + dl]);   // x (bf16) from U
                    float h = (1.f - z) * n + z * xv;
                    HS[row * 136 + dl] = f2bf(h);
                }
            }
        }
    }
    __syncthreads();

    // ---- Phase 2: MLP1 GEMM (K=128, Nout=256) from HS ----
    {
        f32x4 acc[2][4];
        #pragma unroll
        for (int mt = 0; mt < 2; ++mt)
            #pragma unroll
            for (int nl = 0; nl < 4; ++nl) acc[mt][nl] = (f32x4){0.f, 0.f, 0.f, 0.f};

        for (int kt = 0; kt < 4; ++kt) {
            bf16x8 a0 = *(const bf16x8*)(&HS[((l & 15)) * 136 + kt * 32 + (l >> 4) * 8]);
            bf16x8 a1 = *(const bf16x8*)(&HS[(16 + (l & 15)) * 136 + kt * 32 + (l >> 4) * 8]);
            #pragma unroll
            for (int nl = 0; nl < 4; ++nl) {
                int nt = w * 4 + nl;
                bf16x8 b = *(const bf16x8*)(W1p + ((size_t)(nt * 4 + kt) * 64 + l) * 8);
                acc[0][nl] = MFMA(a0, b, acc[0][nl]);
                acc[1][nl] = MFMA(a1, b, acc[1][nl]);
            }
        }

        #pragma unroll
        for (int nl = 0; nl < 4; ++nl) {
            int dcol = (w * 4 + nl) * 16 + (l & 15);
            float bj = b1[dcol];
            float cs = 0.f, cq = 0.f;
            #pragma unroll
            for (int mt = 0; mt < 2; ++mt) {
                #pragma unroll
                for (int j = 0; j < 4; ++j) {
                    int row = mt * 16 + (l >> 4) * 4 + j;
                    float v = acc[mt][nl][j] + bj;
                    v = (v >= 0.f) ? v : 0.01f * v;
                    if (r0 + row < NN) {
                        s1[(size_t)(r0 + row) * HH + dcol] = f2bf(v);
                        cs += v; cq += v * v;
                    }
                }
            }
            cs += __shfl_xor(cs, 16); cs += __shfl_xor(cs, 32);
            cq += __shfl_xor(cq, 16); cq += __shfl_xor(cq, 32);
            if (l < 16) {
                atomicAdd(&sum1[dcol], cs);
                atomicAdd(&sumsq1[dcol], cq);
            }
        }
    }
}

// BN1 fold into W2: W2p = a1*W2 (packed bf16), b2p = b2 + c1 @ W2.
__global__ __launch_bounds__(256) void k_prep2(const float* __restrict__ sum1,
        const float* __restrict__ sumsq1,
        const float* __restrict__ gamma1, const float* __restrict__ beta1,
        const float* __restrict__ W2, const float* __restrict__ b2,
        u16* __restrict__ W2p, float* __restrict__ b2p) {
    __shared__ float a1s[HH], c1s[HH];
    int t = threadIdx.x;
    {
        float m = sum1[t] * (1.f / NN);
        float var = sumsq1[t] * (1.f / NN) - m * m;
        float a = gamma1[t] * rsqrtf(var + BN_EPS);
        a1s[t] = a;
        c1s[t] = beta1[t] - a * m;
    }
    __syncthreads();
    if (blockIdx.x < 128) {
        int idx = blockIdx.x * 256 + t;       // 32768 elems
        int k = idx >> 7, j = idx & 127;
        W2p[packB(k, j, 8)] = f2bf(a1s[k] * W2[k * DD + j]);
    } else if (t < DD) {
        float acc = b2[t];
        for (int k = 0; k < HH; ++k) acc = fmaf(c1s[k], W2[k * DD + t], acc);
        b2p[t] = acc;
    }
}

// mlp2: s2 = leaky(s1 @ W2p + b2p) (f32 out) + column stats.
__global__ __launch_bounds__(256) void k_mlp2(const u16* __restrict__ s1,
        const u16* __restrict__ W2p, const float* __restrict__ b2p,
        float* __restrict__ s2, float* __restrict__ sum2, float* __restrict__ sumsq2) {
    __shared__ u16 A[32 * 264];
    int t = threadIdx.x;
    int r0 = blockIdx.x * 32;
    int w = t >> 6, l = t & 63;

    #pragma unroll
    for (int it = 0; it < 4; ++it) {
        int i = t + it * 256;
        int row = i >> 5, c = i & 31;
        uint4 v = make_uint4(0, 0, 0, 0);
        if (r0 + row < NN) v = *(const uint4*)(s1 + (size_t)(r0 + row) * HH + c * 8);
        *(uint4*)(&A[row * 264 + c * 8]) = v;
    }
    __syncthreads();

    f32x4 acc[2][2];
    #pragma unroll
    for (int mt = 0; mt < 2; ++mt)
        #pragma unroll
        for (int q = 0; q < 2; ++q) acc[mt][q] = (f32x4){0.f, 0.f, 0.f, 0.f};

    for (int kt = 0; kt < 8; ++kt) {
        bf16x8 a0 = *(const bf16x8*)(&A[((l & 15)) * 264 + kt * 32 + (l >> 4) * 8]);
        bf16x8 a1 = *(const bf16x8*)(&A[(16 + (l & 15)) * 264 + kt * 32 + (l >> 4) * 8]);
        #pragma unroll
        for (int q = 0; q < 2; ++q) {
            int nt = w * 2 + q;
            bf16x8 b = *(const bf16x8*)(W2p + ((size_t)(nt * 8 + kt) * 64 + l) * 8);
            acc[0][q] = MFMA(a0, b, acc[0][q]);
            acc[1][q] = MFMA(a1, b, acc[1][q]);
        }
    }

    #pragma unroll
    for (int q = 0; q < 2; ++q) {
        int dcol = (w * 2 + q) * 16 + (l & 15);
        float bj = b2p[dcol];
        float cs = 0.f, cq = 0.f;
        #pragma unroll
        for (int mt = 0; mt < 2; ++mt) {
            #pragma unroll
            for (int j = 0; j < 4; ++j) {
                int row = mt * 16 + (l >> 4) * 4 + j;
                float v = acc[mt][q][j] + bj;
                v = (v >= 0.f) ? v : 0.01f * v;
                if (r0 + row < NN) {
                    s2[(size_t)(r0 + row) * DD + dcol] = v;
                    cs += v; cq += v * v;
                }
            }
        }
        cs += __shfl_xor(cs, 16); cs += __shfl_xor(cs, 32);
        cq += __shfl_xor(cq, 16); cq += __shfl_xor(cq, 32);
        if (l < 16) {
            atomicAdd(&sum2[dcol], cs);
            atomicAdd(&sumsq2[dcol], cq);
        }
    }
}

__global__ __launch_bounds__(256) void k_bn_out(const float* __restrict__ s2,
        const float* __restrict__ sum2, const float* __restrict__ sumsq2,
        const float* __restrict__ gamma2, const float* __restrict__ beta2,
        float* __restrict__ out) {
    __shared__ float a2s[DD], c2s[DD];
    int t = threadIdx.x;
    if (t < DD) {
        float m = sum2[t] * (1.f / NN);
        float var = sumsq2[t] * (1.f / NN) - m * m;
        float a = gamma2[t] * rsqrtf(var + BN_EPS);
        a2s[t] = a;
        c2s[t] = beta2[t] - a * m;
    }
    __syncthreads();
    int tid = blockIdx.x * 256 + t;
    if (tid >= NN * DD / 4) return;
    int c4 = (tid & 31) * 4;
    float4 v = ((const float4*)s2)[tid];
    float4 o;
    o.x = a2s[c4 + 0] * v.x + c2s[c4 + 0];
    o.y = a2s[c4 + 1] * v.y + c2s[c4 + 1];
    o.z = a2s[c4 + 2] * v.z + c2s[c4 + 2];
    o.w = a2s[c4 + 3] * v.w + c2s[c4 + 3];
    ((float4*)out)[tid] = o;
}

// ---------------------------------------------------------------------------
extern "C" void kernel_launch(void* const* d_in, const int* in_sizes, int n_in,
                              void* d_out, int out_size, void* d_ws, size_t ws_size,
                              hipStream_t stream) {
    const float* x       = (const float*)d_in[0];
    const int*   edges   = (const int*)d_in[1];
    const float* merge_W = (const float*)d_in[2];
    const float* merge_b = (const float*)d_in[3];
    const float* W_ih    = (const float*)d_in[4];
    const float* W_hh    = (const float*)d_in[5];
    const float* b_ih    = (const float*)d_in[6];
    const float* b_hh    = (const float*)d_in[7];
    const float* W1      = (const float*)d_in[8];
    const float* b1      = (const float*)d_in[9];
    const float* gamma1  = (const float*)d_in[10];
    const float* beta1   = (const float*)d_in[11];
    const float* W2      = (const float*)d_in[12];
    const float* b2      = (const float*)d_in[13];
    const float* gamma2  = (const float*)d_in[14];
    const float* beta2   = (const float*)d_in[15];
    float* out = (float*)d_out;

    // ws layout (bytes):
    //  [0, 12.8M):      xb (bf16 x)                       — dead after gru_mlp1
    //  [12.8M, 25.6M):  asumb     \  overlaid by s2 (f32, 25.6MB, [12.8M,38.4M))
    //  [25.6M, 38.4M):  amaxb     /  after gru_mlp1
    //  [38.4M, 64.0M):  s1 (bf16, 25.6MB)
    //  [64.0M, ...):    packed weights, biases, stats, CSR
    char* wsb = (char*)d_ws;
    u16*   xb     = (u16*)(wsb + 0);
    u16*   asumb  = (u16*)(wsb + 12800000);
    u16*   amaxb  = (u16*)(wsb + 25600000);
    float* s2     = (float*)(wsb + 12800000);
    u16*   s1b    = (u16*)(wsb + 38400000);
    u16*   Wpg    = (u16*)(wsb + 64000000);    // 393,216 B
    u16*   W1p    = (u16*)(wsb + 64393216);    // 65,536 B
    u16*   W2p    = (u16*)(wsb + 64458752);    // 65,536 B
    float* bg     = (float*)(wsb + 64524288);  // 2,048 B
    float* b2p    = (float*)(wsb + 64526336);  // 512 B
    float* stats  = (float*)(wsb + 64526848);  // 3,072 B
    float* sum1   = stats;
    float* sumsq1 = stats + 256;
    float* sum2   = stats + 512;
    float* sumsq2 = stats + 640;
    int*   deg    = (int*)(wsb + 64529920);    // 50,000 ints (scan in place)
    int*   rowptr = (int*)(wsb + 64729920);    // 50,001 ints
    int*   cursor = (int*)(wsb + 64929924);    // 50,000 ints
    int*   eidx   = (int*)(wsb + 65129924);    // 600,000 ints
    int*   bsum   = (int*)(wsb + 67529924);    // 98 ints
    int*   boff   = (int*)(wsb + 67530316);    // 98 ints
    // total ~67.5 MB

    const int NB = (NN + 31) / 32;        // 1563
    const int NBLK = (NN + 511) / 512;    // 98

    k_init<<<(NN + 255) / 256, 256, 0, stream>>>(deg, stats);
    k_count<<<(NE + 255) / 256, 256, 0, stream>>>(edges, deg);
    k_scanA<<<NBLK, 256, 0, stream>>>(deg, deg, bsum);
    k_scanB<<<1, 128, 0, stream>>>(bsum, boff);
    k_scanC<<<(NN + 255) / 256, 256, 0, stream>>>(deg, boff, rowptr, cursor);
    k_fill<<<(NE + 255) / 256, 256, 0, stream>>>(edges, cursor, eidx);
    k_xcast<<<(NN * DD / 8 + 255) / 256, 256, 0, stream>>>((const float4*)x, (uint4*)xb);
    k_prep_w<<<898, 256, 0, stream>>>(merge_W, W_ih, W_hh, merge_b, b_ih, b_hh, W1,
                                      Wpg, bg, W1p);
    k_aggregate<<<(NN * 64) / 256 + 1, 256, 0, stream>>>((const unsigned*)xb, rowptr, eidx,
                                                         (unsigned*)asumb, (unsigned*)amaxb);
    k_gru_mlp1<<<NB, 256, 0, stream>>>(asumb, amaxb, xb, Wpg, bg, W1p, b1,
                                       s1b, sum1, sumsq1);
    k_prep2<<<129, 256, 0, stream>>>(sum1, sumsq1, gamma1, beta1, W2, b2, W2p, b2p);
    k_mlp2<<<NB, 256, 0, stream>>>(s1b, W2p, b2p, s2, sum2, sumsq2);
    k_bn_out<<<6250, 256, 0, stream>>>(s2, sum2, sumsq2, gamma2, beta2, out);
}

// Round 11
// 323.106 us; speedup vs baseline: 9.7467x; 1.2371x over previous
//
#include <hip/hip_runtime.h>
#include <hip/hip_bf16.h>
#include <math.h>

#define NN 50000
#define NE 600000
#define DD 128
#define HH 256
#define BN_EPS 1e-5f

typedef unsigned short u16;
typedef short bf16x8 __attribute__((ext_vector_type(8)));
typedef float f32x4 __attribute__((ext_vector_type(4)));

__device__ __forceinline__ u16 f2bf(float f) {
    unsigned int u = __float_as_uint(f);
    unsigned int r = (u + 0x7fffu + ((u >> 16) & 1u)) >> 16;
    return (u16)r;
}
__device__ __forceinline__ float bf2f(u16 b) {
    return __uint_as_float(((unsigned int)b) << 16);
}
#define MFMA(a, b, c) __builtin_amdgcn_mfma_f32_16x16x32_bf16((a), (b), (c), 0, 0, 0)

// ---------------------------------------------------------------------------
__global__ __launch_bounds__(256) void k_init(int* __restrict__ deg,
                                              float* __restrict__ stats) {
    int tid = blockIdx.x * 256 + threadIdx.x;
    if (tid < NN) deg[tid] = 0;
    if (tid < 768) stats[tid] = 0.f;
}

__global__ __launch_bounds__(256) void k_count(const int* __restrict__ edges,
                                               int* __restrict__ deg) {
    int e = blockIdx.x * 256 + threadIdx.x;
    if (e >= NE) return;
    atomicAdd(&deg[edges[NE + e]], 1);
}

// Hierarchical exclusive scan of deg[NN].
__global__ __launch_bounds__(256) void k_scanA(const int* __restrict__ deg,
                                               int* __restrict__ loc,
                                               int* __restrict__ bsum) {
    __shared__ int s[256];
    int b = blockIdx.x, t = threadIdx.x;
    int i0 = b * 512 + t * 2;
    int d0 = (i0 < NN) ? deg[i0] : 0;
    int d1 = (i0 + 1 < NN) ? deg[i0 + 1] : 0;
    s[t] = d0 + d1;
    __syncthreads();
    for (int off = 1; off < 256; off <<= 1) {
        int v = (t >= off) ? s[t - off] : 0;
        __syncthreads();
        s[t] += v;
        __syncthreads();
    }
    int excl = (t > 0) ? s[t - 1] : 0;
    if (i0 < NN) loc[i0] = excl;
    if (i0 + 1 < NN) loc[i0 + 1] = excl + d0;
    if (t == 255) bsum[b] = s[255];
}

__global__ __launch_bounds__(128) void k_scanB(const int* __restrict__ bsum,
                                               int* __restrict__ boff) {
    __shared__ int s[128];
    int t = threadIdx.x;
    const int NBLK = (NN + 511) / 512;   // 98
    s[t] = (t < NBLK) ? bsum[t] : 0;
    __syncthreads();
    for (int off = 1; off < 128; off <<= 1) {
        int v = (t >= off) ? s[t - off] : 0;
        __syncthreads();
        s[t] += v;
        __syncthreads();
    }
    if (t < NBLK) boff[t] = (t > 0) ? s[t - 1] : 0;
}

__global__ __launch_bounds__(256) void k_scanC(const int* __restrict__ loc,
                                               const int* __restrict__ boff,
                                               int* __restrict__ rowptr,
                                               int* __restrict__ cursor) {
    int i = blockIdx.x * 256 + threadIdx.x;
    if (i < NN) {
        int v = loc[i] + boff[i >> 9];
        rowptr[i] = v;
        cursor[i] = v;
    }
    if (i == 0) rowptr[NN] = NE;
}

__global__ __launch_bounds__(256) void k_fill(const int* __restrict__ edges,
                                              int* __restrict__ cursor,
                                              int* __restrict__ eidx) {
    int e = blockIdx.x * 256 + threadIdx.x;
    if (e >= NE) return;
    int src = edges[e];
    int dst = edges[NE + e];
    int slot = atomicAdd(&cursor[dst], 1);
    eidx[slot] = src;
}

// x f32 -> bf16 (8 elems/thread)
__global__ __launch_bounds__(256) void k_xcast(const float4* __restrict__ x4,
                                               uint4* __restrict__ xb4) {
    int tid = blockIdx.x * 256 + threadIdx.x;
    if (tid >= NN * DD / 8) return;
    float4 a = x4[tid * 2];
    float4 b = x4[tid * 2 + 1];
    uint4 o;
    o.x = (unsigned)f2bf(a.x) | ((unsigned)f2bf(a.y) << 16);
    o.y = (unsigned)f2bf(a.z) | ((unsigned)f2bf(a.w) << 16);
    o.z = (unsigned)f2bf(b.x) | ((unsigned)f2bf(b.y) << 16);
    o.w = (unsigned)f2bf(b.z) | ((unsigned)f2bf(b.w) << 16);
    xb4[tid] = o;
}

// ---------------------------------------------------------------------------
// One wave per node; 4-way unrolled gather for memory-level parallelism.
__global__ __launch_bounds__(256) void k_aggregate(const unsigned* __restrict__ xb,
        const int* __restrict__ rowptr, const int* __restrict__ eidx,
        unsigned* __restrict__ asum, unsigned* __restrict__ amax) {
    int gid = blockIdx.x * 256 + threadIdx.x;
    int node = gid >> 6;
    int lane = threadIdx.x & 63;
    if (node >= NN) return;
    int beg = rowptr[node], end = rowptr[node + 1];
    float sx = 0.f, sy = 0.f;
    const float NINF = -__builtin_inff();
    float mx = NINF, my = NINF;
    int j = beg;
    for (; j + 4 <= end; j += 4) {
        int i0 = eidx[j], i1 = eidx[j + 1], i2 = eidx[j + 2], i3 = eidx[j + 3];
        unsigned v0 = xb[(size_t)i0 * 64 + lane];
        unsigned v1 = xb[(size_t)i1 * 64 + lane];
        unsigned v2 = xb[(size_t)i2 * 64 + lane];
        unsigned v3 = xb[(size_t)i3 * 64 + lane];
        float a0 = bf2f((u16)(v0 & 0xffff)), b0 = bf2f((u16)(v0 >> 16));
        float a1 = bf2f((u16)(v1 & 0xffff)), b1 = bf2f((u16)(v1 >> 16));
        float a2 = bf2f((u16)(v2 & 0xffff)), b2 = bf2f((u16)(v2 >> 16));
        float a3 = bf2f((u16)(v3 & 0xffff)), b3 = bf2f((u16)(v3 >> 16));
        sx += a0 + a1 + a2 + a3;
        sy += b0 + b1 + b2 + b3;
        mx = fmaxf(fmaxf(fmaxf(mx, a0), fmaxf(a1, a2)), a3);
        my = fmaxf(fmaxf(fmaxf(my, b0), fmaxf(b1, b2)), b3);
    }
    for (; j < end; ++j) {
        int src = eidx[j];
        unsigned v = xb[(size_t)src * 64 + lane];
        float vx = bf2f((u16)(v & 0xffff));
        float vy = bf2f((u16)(v >> 16));
        sx += vx; sy += vy;
        mx = fmaxf(mx, vx); my = fmaxf(my, vy);
    }
    if (beg == end) { mx = 0.f; my = 0.f; }
    asum[(size_t)node * 64 + lane] = (unsigned)f2bf(sx) | ((unsigned)f2bf(sy) << 16);
    amax[(size_t)node * 64 + lane] = (unsigned)f2bf(mx) | ((unsigned)f2bf(my) << 16);
}

// ---------------------------------------------------------------------------
// Pack helper: B-fragment layout for mfma_f32_16x16x32_bf16.
// lane l holds B[k=(l>>4)*8+e][n=l&15]; flat = ((nt*KT+kt)*64+l)*8+e.
__device__ __forceinline__ size_t packB(int k, int n, int KT) {
    int nt = n >> 4;
    int kt = k >> 5;
    int lane = (n & 15) | (((k >> 3) & 3) << 4);
    int e = k & 7;
    return ((size_t)(nt * KT + kt) * 64 + lane) * 8 + e;
}

// Merged weight prep: blocks [0,768) -> W_gru pack; [768,770) -> gru bias;
// [770,898) -> W1 pack.
__global__ __launch_bounds__(256) void k_prep_w(const float* __restrict__ merge_W,
        const float* __restrict__ W_ih, const float* __restrict__ W_hh,
        const float* __restrict__ merge_b,
        const float* __restrict__ b_ih, const float* __restrict__ b_hh,
        const float* __restrict__ W1,
        u16* __restrict__ Wp, float* __restrict__ bg, u16* __restrict__ W1p) {
    int bid = blockIdx.x, t = threadIdx.x;
    if (bid < 768) {
        int tid = bid * 256 + t;               // 0 .. 384*512
        int k = tid >> 9;
        int jout = tid & 511;
        float v = 0.f;
        if (jout < 256) {          // r,z: summed i+h contributions
            int j = jout;
            if (k < 256) {
                float acc = 0.f;
                for (int q = 0; q < DD; ++q) acc += merge_W[k * DD + q] * W_ih[j * DD + q];
                v = acc;
            } else v = W_hh[j * DD + (k - 256)];
        } else if (jout < 384) {   // i_n
            int j = jout;
            if (k < 256) {
                float acc = 0.f;
                for (int q = 0; q < DD; ++q) acc += merge_W[k * DD + q] * W_ih[j * DD + q];
                v = acc;
            }
        } else {                   // h_n
            int j = jout - 128;
            if (k >= 256) v = W_hh[j * DD + (k - 256)];
        }
        Wp[packB(k, jout, 12)] = f2bf(v);
    } else if (bid < 770) {
        int jout = (bid - 768) * 256 + t;      // 0..512
        float v;
        if (jout < 384) {
            int j = jout;
            float acc = b_ih[j];
            for (int q = 0; q < DD; ++q) acc += merge_b[q] * W_ih[j * DD + q];
            v = (jout < 256) ? acc + b_hh[j] : acc;
        } else {
            v = b_hh[jout - 128];
        }
        bg[jout] = v;
    } else {
        int tid = (bid - 770) * 256 + t;       // 0 .. 128*256
        int k = tid >> 8;
        int j = tid & 255;
        W1p[packB(k, j, 4)] = f2bf(W1[tid]);
    }
}

// ---------------------------------------------------------------------------
// Fused GRU + MLP1, 64 rows/block, 512 threads (8 waves).
// Wave w owns d-tile w (16 cols): GRU nt = g*8+w (4 B loads : 16 MFMAs/kt),
// MLP1 nt = w*2+nl. h lives only in LDS (HS).
__global__ __launch_bounds__(512, 4) void k_gru_mlp1(const u16* __restrict__ asum,
        const u16* __restrict__ amax, const u16* __restrict__ xb,
        const u16* __restrict__ Wp, const float* __restrict__ bg,
        const u16* __restrict__ W1p, const float* __restrict__ b1,
        u16* __restrict__ s1, float* __restrict__ sum1, float* __restrict__ sumsq1) {
    __shared__ u16 U[64 * 392];     // [asum|amax|x] + 8 pad = 50.2 KB
    __shared__ u16 HS[64 * 136];    // h + 8 pad = 17.4 KB
    int t = threadIdx.x;
    int r0 = blockIdx.x * 64;
    int w = t >> 6, l = t & 63;     // w in 0..7

    #pragma unroll
    for (int src = 0; src < 3; ++src) {
        const u16* p = (src == 0) ? asum : (src == 1) ? amax : xb;
        #pragma unroll
        for (int it = 0; it < 2; ++it) {
            int i = t + it * 512;            // 1024 chunks of 8 bf16
            int row = i >> 4, c = i & 15;
            uint4 v = make_uint4(0, 0, 0, 0);
            if (r0 + row < NN) v = *(const uint4*)(p + (size_t)(r0 + row) * DD + c * 8);
            *(uint4*)(&U[row * 392 + src * DD + c * 8]) = v;
        }
    }
    __syncthreads();

    // ---- Phase 1: GRU GEMM (K=384, Nout=512) ----
    {
        f32x4 acc[4][4];
        #pragma unroll
        for (int mt = 0; mt < 4; ++mt)
            #pragma unroll
            for (int g = 0; g < 4; ++g) acc[mt][g] = (f32x4){0.f, 0.f, 0.f, 0.f};

        #pragma unroll 2
        for (int kt = 0; kt < 12; ++kt) {
            bf16x8 b[4];
            #pragma unroll
            for (int g = 0; g < 4; ++g) {
                int nt = g * 8 + w;
                b[g] = *(const bf16x8*)(Wp + ((size_t)(nt * 12 + kt) * 64 + l) * 8);
            }
            bf16x8 a[4];
            #pragma unroll
            for (int mt = 0; mt < 4; ++mt)
                a[mt] = *(const bf16x8*)(&U[(mt * 16 + (l & 15)) * 392 + kt * 32 + (l >> 4) * 8]);
            #pragma unroll
            for (int mt = 0; mt < 4; ++mt) {
                #pragma unroll
                for (int g = 0; g < 4; ++g)
                    acc[mt][g] = MFMA(a[mt], b[g], acc[mt][g]);
            }
        }

        int dl = w * 16 + (l & 15);      // 0..127
        float br = bg[dl], bz = bg[128 + dl], bi = bg[256 + dl], bh = bg[384 + dl];
        #pragma unroll
        for (int mt = 0; mt < 4; ++mt) {
            #pragma unroll
            for (int j = 0; j < 4; ++j) {
                int row = mt * 16 + (l >> 4) * 4 + j;
                float rp = acc[mt][0][j] + br;
                float zp = acc[mt][1][j] + bz;
                float ip = acc[mt][2][j] + bi;
                float hp = acc[mt][3][j] + bh;
                float r = 1.f / (1.f + __expf(-rp));
                float z = 1.f / (1.f + __expf(-zp));
                float n = tanhf(ip + r * hp);
                float xv = bf2f(U[row * 392 + 2 * DD + dl]);   // x (bf16) from U
                float h = (1.f - z) * n + z * xv;
                HS[row * 136 + dl] = f2bf(h);
            }
        }
    }
    __syncthreads();

    // ---- Phase 2: MLP1 GEMM (K=128, Nout=256) from HS ----
    {
        f32x4 acc[4][2];
        #pragma unroll
        for (int mt = 0; mt < 4; ++mt)
            #pragma unroll
            for (int nl = 0; nl < 2; ++nl) acc[mt][nl] = (f32x4){0.f, 0.f, 0.f, 0.f};

        #pragma unroll 2
        for (int kt = 0; kt < 4; ++kt) {
            bf16x8 b[2];
            #pragma unroll
            for (int nl = 0; nl < 2; ++nl) {
                int nt = w * 2 + nl;
                b[nl] = *(const bf16x8*)(W1p + ((size_t)(nt * 4 + kt) * 64 + l) * 8);
            }
            bf16x8 a[4];
            #pragma unroll
            for (int mt = 0; mt < 4; ++mt)
                a[mt] = *(const bf16x8*)(&HS[(mt * 16 + (l & 15)) * 136 + kt * 32 + (l >> 4) * 8]);
            #pragma unroll
            for (int mt = 0; mt < 4; ++mt) {
                #pragma unroll
                for (int nl = 0; nl < 2; ++nl)
                    acc[mt][nl] = MFMA(a[mt], b[nl], acc[mt][nl]);
            }
        }

        #pragma unroll
        for (int nl = 0; nl < 2; ++nl) {
            int dcol = (w * 2 + nl) * 16 + (l & 15);
            float bj = b1[dcol];
            float cs = 0.f, cq = 0.f;
            #pragma unroll
            for (int mt = 0; mt < 4; ++mt) {
                #pragma unroll
                for (int j = 0; j < 4; ++j) {
                    int row = mt * 16 + (l >> 4) * 4 + j;
                    float v = acc[mt][nl][j] + bj;
                    v = (v >= 0.f) ? v : 0.01f * v;
                    if (r0 + row < NN) {
                        s1[(size_t)(r0 + row) * HH + dcol] = f2bf(v);
                        cs += v; cq += v * v;
                    }
                }
            }
            cs += __shfl_xor(cs, 16); cs += __shfl_xor(cs, 32);
            cq += __shfl_xor(cq, 16); cq += __shfl_xor(cq, 32);
            if (l < 16) {
                atomicAdd(&sum1[dcol], cs);
                atomicAdd(&sumsq1[dcol], cq);
            }
        }
    }
}

// BN1 fold into W2: W2p = a1*W2 (packed bf16), b2p = b2 + c1 @ W2.
__global__ __launch_bounds__(256) void k_prep2(const float* __restrict__ sum1,
        const float* __restrict__ sumsq1,
        const float* __restrict__ gamma1, const float* __restrict__ beta1,
        const float* __restrict__ W2, const float* __restrict__ b2,
        u16* __restrict__ W2p, float* __restrict__ b2p) {
    __shared__ float a1s[HH], c1s[HH];
    int t = threadIdx.x;
    {
        float m = sum1[t] * (1.f / NN);
        float var = sumsq1[t] * (1.f / NN) - m * m;
        float a = gamma1[t] * rsqrtf(var + BN_EPS);
        a1s[t] = a;
        c1s[t] = beta1[t] - a * m;
    }
    __syncthreads();
    if (blockIdx.x < 128) {
        int idx = blockIdx.x * 256 + t;       // 32768 elems
        int k = idx >> 7, j = idx & 127;
        W2p[packB(k, j, 8)] = f2bf(a1s[k] * W2[k * DD + j]);
    } else if (t < DD) {
        float acc = b2[t];
        for (int k = 0; k < HH; ++k) acc = fmaf(c1s[k], W2[k * DD + t], acc);
        b2p[t] = acc;
    }
}

// mlp2: 64 rows/block, 512 threads (8 waves); wave w owns n-tile w.
// Per kt: 1 B load : 4 MFMAs.
__global__ __launch_bounds__(512, 4) void k_mlp2(const u16* __restrict__ s1,
        const u16* __restrict__ W2p, const float* __restrict__ b2p,
        float* __restrict__ s2, float* __restrict__ sum2, float* __restrict__ sumsq2) {
    __shared__ u16 A[64 * 264];     // 33.8 KB
    int t = threadIdx.x;
    int r0 = blockIdx.x * 64;
    int w = t >> 6, l = t & 63;

    #pragma unroll
    for (int it = 0; it < 4; ++it) {
        int i = t + it * 512;                // 2048 chunks
        int row = i >> 5, c = i & 31;
        uint4 v = make_uint4(0, 0, 0, 0);
        if (r0 + row < NN) v = *(const uint4*)(s1 + (size_t)(r0 + row) * HH + c * 8);
        *(uint4*)(&A[row * 264 + c * 8]) = v;
    }
    __syncthreads();

    f32x4 acc[4];
    #pragma unroll
    for (int mt = 0; mt < 4; ++mt) acc[mt] = (f32x4){0.f, 0.f, 0.f, 0.f};

    #pragma unroll 2
    for (int kt = 0; kt < 8; ++kt) {
        bf16x8 b = *(const bf16x8*)(W2p + ((size_t)(w * 8 + kt) * 64 + l) * 8);
        bf16x8 a[4];
        #pragma unroll
        for (int mt = 0; mt < 4; ++mt)
            a[mt] = *(const bf16x8*)(&A[(mt * 16 + (l & 15)) * 264 + kt * 32 + (l >> 4) * 8]);
        #pragma unroll
        for (int mt = 0; mt < 4; ++mt)
            acc[mt] = MFMA(a[mt], b, acc[mt]);
    }

    int dcol = w * 16 + (l & 15);
    float bj = b2p[dcol];
    float cs = 0.f, cq = 0.f;
    #pragma unroll
    for (int mt = 0; mt < 4; ++mt) {
        #pragma unroll
        for (int j = 0; j < 4; ++j) {
            int row = mt * 16 + (l >> 4) * 4 + j;
            float v = acc[mt][j] + bj;
            v = (v >= 0.f) ? v : 0.01f * v;
            if (r0 + row < NN) {
                s2[(size_t)(r0 + row) * DD + dcol] = v;
                cs += v; cq += v * v;
            }
        }
    }
    cs += __shfl_xor(cs, 16); cs += __shfl_xor(cs, 32);
    cq += __shfl_xor(cq, 16); cq += __shfl_xor(cq, 32);
    if (l < 16) {
        atomicAdd(&sum2[dcol], cs);
        atomicAdd(&sumsq2[dcol], cq);
    }
}

__global__ __launch_bounds__(256) void k_bn_out(const float* __restrict__ s2,
        const float* __restrict__ sum2, const float* __restrict__ sumsq2,
        const float* __restrict__ gamma2, const float* __restrict__ beta2,
        float* __restrict__ out) {
    __shared__ float a2s[DD], c2s[DD];
    int t = threadIdx.x;
    if (t < DD) {
        float m = sum2[t] * (1.f / NN);
        float var = sumsq2[t] * (1.f / NN) - m * m;
        float a = gamma2[t] * rsqrtf(var + BN_EPS);
        a2s[t] = a;
        c2s[t] = beta2[t] - a * m;
    }
    __syncthreads();
    int tid = blockIdx.x * 256 + t;
    if (tid >= NN * DD / 4) return;
    int c4 = (tid & 31) * 4;
    float4 v = ((const float4*)s2)[tid];
    float4 o;
    o.x = a2s[c4 + 0] * v.x + c2s[c4 + 0];
    o.y = a2s[c4 + 1] * v.y + c2s[c4 + 1];
    o.z = a2s[c4 + 2] * v.z + c2s[c4 + 2];
    o.w = a2s[c4 + 3] * v.w + c2s[c4 + 3];
    ((float4*)out)[tid] = o;
}

// ---------------------------------------------------------------------------
extern "C" void kernel_launch(void* const* d_in, const int* in_sizes, int n_in,
                              void* d_out, int out_size, void* d_ws, size_t ws_size,
                              hipStream_t stream) {
    const float* x       = (const float*)d_in[0];
    const int*   edges   = (const int*)d_in[1];
    const float* merge_W = (const float*)d_in[2];
    const float* merge_b = (const float*)d_in[3];
    const float* W_ih    = (const float*)d_in[4];
    const float* W_hh    = (const float*)d_in[5];
    const float* b_ih    = (const float*)d_in[6];
    const float* b_hh    = (const float*)d_in[7];
    const float* W1      = (const float*)d_in[8];
    const float* b1      = (const float*)d_in[9];
    const float* gamma1  = (const float*)d_in[10];
    const float* beta1   = (const float*)d_in[11];
    const float* W2      = (const float*)d_in[12];
    const float* b2      = (const float*)d_in[13];
    const float* gamma2  = (const float*)d_in[14];
    const float* beta2   = (const float*)d_in[15];
    float* out = (float*)d_out;

    // ws layout (bytes):
    char* wsb = (char*)d_ws;
    u16*   xb     = (u16*)(wsb + 0);
    u16*   asumb  = (u16*)(wsb + 12800000);
    u16*   amaxb  = (u16*)(wsb + 25600000);
    float* s2     = (float*)(wsb + 12800000);
    u16*   s1b    = (u16*)(wsb + 38400000);
    u16*   Wpg    = (u16*)(wsb + 64000000);    // 393,216 B
    u16*   W1p    = (u16*)(wsb + 64393216);    // 65,536 B
    u16*   W2p    = (u16*)(wsb + 64458752);    // 65,536 B
    float* bg     = (float*)(wsb + 64524288);  // 2,048 B
    float* b2p    = (float*)(wsb + 64526336);  // 512 B
    float* stats  = (float*)(wsb + 64526848);  // 3,072 B
    float* sum1   = stats;
    float* sumsq1 = stats + 256;
    float* sum2   = stats + 512;
    float* sumsq2 = stats + 640;
    int*   deg    = (int*)(wsb + 64529920);    // 50,000 ints (scan in place)
    int*   rowptr = (int*)(wsb + 64729920);    // 50,001 ints
    int*   cursor = (int*)(wsb + 64929924);    // 50,000 ints
    int*   eidx   = (int*)(wsb + 65129924);    // 600,000 ints
    int*   bsum   = (int*)(wsb + 67529924);    // 98 ints
    int*   boff   = (int*)(wsb + 67530316);    // 98 ints
    // total ~67.5 MB

    const int NB64 = (NN + 63) / 64;      // 782
    const int NBLK = (NN + 511) / 512;    // 98

    k_init<<<(NN + 255) / 256, 256, 0, stream>>>(deg, stats);
    k_count<<<(NE + 255) / 256, 256, 0, stream>>>(edges, deg);
    k_scanA<<<NBLK, 256, 0, stream>>>(deg, deg, bsum);
    k_scanB<<<1, 128, 0, stream>>>(bsum, boff);
    k_scanC<<<(NN + 255) / 256, 256, 0, stream>>>(deg, boff, rowptr, cursor);
    k_fill<<<(NE + 255) / 256, 256, 0, stream>>>(edges, cursor, eidx);
    k_xcast<<<(NN * DD / 8 + 255) / 256, 256, 0, stream>>>((const float4*)x, (uint4*)xb);
    k_prep_w<<<898, 256, 0, stream>>>(merge_W, W_ih, W_hh, merge_b, b_ih, b_hh, W1,
                                      Wpg, bg, W1p);
    k_aggregate<<<(NN * 64) / 256 + 1, 256, 0, stream>>>((const unsigned*)xb, rowptr, eidx,
                                                         (unsigned*)asumb, (unsigned*)amaxb);
    k_gru_mlp1<<<NB64, 512, 0, stream>>>(asumb, amaxb, xb, Wpg, bg, W1p, b1,
                                         s1b, sum1, sumsq1);
    k_prep2<<<129, 256, 0, stream>>>(sum1, sumsq1, gamma1, beta1, W2, b2, W2p, b2p);
    k_mlp2<<<NB64, 512, 0, stream>>>(s1b, W2p, b2p, s2, sum2, sumsq2);
    k_bn_out<<<6250, 256, 0, stream>>>(s2, sum2, sumsq2, gamma2, beta2, out);
}